// Round 2
// baseline (234.414 us; speedup 1.0000x reference)
//
#include <hip/hip_runtime.h>

typedef unsigned short u16;
typedef __bf16 bf16x8 __attribute__((ext_vector_type(8)));
typedef float f32x4 __attribute__((ext_vector_type(4)));
typedef u16 u16x8 __attribute__((ext_vector_type(8)));

#define NUM_HEADS 16
#define HIDDEN 1024
#define BATCH 4
#define SEQ 1024
// 0.125 * log2(e): fold the 1/sqrt(64) scale and the exp->exp2 conversion
#define C1 0.1803368809109783f
#define LOG2E 1.4426950408889634f

#define VMCNT0 asm volatile("s_waitcnt vmcnt(0)" ::: "memory")
#define VMCNT4 asm volatile("s_waitcnt vmcnt(4)" ::: "memory")
#define BAR __builtin_amdgcn_s_barrier()
#define SCHED0 __builtin_amdgcn_sched_barrier(0)

static __device__ __forceinline__ u16 f2bf(float x) {
  unsigned u = __float_as_uint(x);
  u = u + 0x7FFFu + ((u >> 16) & 1u);
  return (u16)(u >> 16);
}
static __device__ __forceinline__ float bf2f(u16 b) {
  return __uint_as_float(((unsigned)b) << 16);
}
static __device__ __forceinline__ void async16(u16* lds, const u16* g) {
  __builtin_amdgcn_global_load_lds(
      (const __attribute__((address_space(1))) void*)g,
      (__attribute__((address_space(3))) void*)lds, 16, 0, 0);
}

// ---------------- prep: fp32 -> bf16 (x8 per thread), z selects tensor ----------------
__global__ void k_cvt(const float* __restrict__ in0, u16* __restrict__ out0,
                      const float* __restrict__ in1, u16* __restrict__ out1, int n8) {
  int i = blockIdx.x * 256 + threadIdx.x;
  if (i >= n8) return;
  const float* in = blockIdx.z ? in1 : in0;
  u16* out = blockIdx.z ? out1 : out0;
  float4 a = ((const float4*)in)[i * 2];
  float4 b = ((const float4*)in)[i * 2 + 1];
  u16x8 v;
  v[0] = f2bf(a.x); v[1] = f2bf(a.y); v[2] = f2bf(a.z); v[3] = f2bf(a.w);
  v[4] = f2bf(b.x); v[5] = f2bf(b.y); v[6] = f2bf(b.z); v[7] = f2bf(b.w);
  *(u16x8*)&out[(size_t)i * 8] = v;
}

// ---------------- prep: W [K][N] fp32 -> Wt [N][K] bf16 ----------------
__global__ void k_wtrans(const float* __restrict__ Wq, const float* __restrict__ Wk,
                         const float* __restrict__ Wv, u16* __restrict__ Wt) {
  __shared__ float tile[64][65];
  const float* W = (blockIdx.z == 0) ? Wq : (blockIdx.z == 1) ? Wk : Wv;
  u16* out = Wt + (size_t)blockIdx.z * HIDDEN * HIDDEN;
  int k0 = blockIdx.y * 64, n0 = blockIdx.x * 64;
  int tid = threadIdx.x;
  int r = tid >> 6, c = tid & 63;
#pragma unroll
  for (int i = 0; i < 16; ++i)
    tile[i * 4 + r][c] = W[(size_t)(k0 + i * 4 + r) * HIDDEN + n0 + c];
  __syncthreads();
#pragma unroll
  for (int i = 0; i < 16; ++i)
    out[(size_t)(n0 + i * 4 + r) * HIDDEN + k0 + c] = f2bf(tile[c][i * 4 + r]);
}

// ---------------- prep: mask -> log2-domain bf16 adder + tile flags ----------------
__global__ void k_mask(const float* __restrict__ mask, u16* __restrict__ adder,
                       int* __restrict__ flags) {
  int tt = blockIdx.x, ft = blockIdx.y, b = blockIdx.z;
  int tid = threadIdx.x;
  __shared__ int sflag;
  if (tid == 0) sflag = 0;
  __syncthreads();
  int any = 0;
  size_t base = ((size_t)b * SEQ + ft * 128) * SEQ + tt * 128;
  for (int i = 0; i < 64; ++i) {
    int idx = i * 256 + tid;
    int r = idx >> 7, c = idx & 127;
    float v = mask[base + (size_t)r * SEQ + c];
    any |= (v != 1.0f);
    adder[base + (size_t)r * SEQ + c] = f2bf((1.0f - v) * -10000.0f * LOG2E);
  }
  if (any) sflag = 1;
  __syncthreads();
  if (tid == 0) flags[(b * 8 + ft) * 8 + tt] = sflag;
}

// ---------------- QKV GEMM: 128x128 tile, BK=64, 2-phase dbuf ----------------
__global__ __launch_bounds__(256) void k_gemm(
    const u16* __restrict__ Af, const u16* __restrict__ At,
    const u16* __restrict__ Wt,
    const float* __restrict__ bq, const float* __restrict__ bk, const float* __restrict__ bv,
    u16* __restrict__ Qh, u16* __restrict__ Kh, u16* __restrict__ Vt) {
  __shared__ u16 sA[2][128 * 64];
  __shared__ u16 sB[2][128 * 64];
  int which = blockIdx.z;
  const u16* A = (which == 0) ? Af : At;
  const u16* B = Wt + (size_t)which * HIDDEN * HIDDEN;
  const float* bias = (which == 0) ? bq : (which == 1) ? bk : bv;
  int m0 = blockIdx.y * 128, n0 = blockIdx.x * 128;
  int tid = threadIdx.x, w = tid >> 6, lane = tid & 63;
  int wr = w >> 1, wc = w & 1;
  int g = lane >> 4, cc = lane & 15;

  f32x4 acc[4][4] = {};

  int sx[4];
  const u16* aptr[4];
  const u16* bptr[4];
#pragma unroll
  for (int i = 0; i < 4; ++i) {
    int ch = w * 4 + i;
    int x = ch * 1024 + lane * 16;
    int row = x >> 7;
    int colb = (x & 127) ^ ((row & 7) << 4);  // pre-swizzled source
    sx[i] = ch * 512;
    aptr[i] = A + (size_t)(m0 + row) * HIDDEN + (colb >> 1);
    bptr[i] = B + (size_t)(n0 + row) * HIDDEN + (colb >> 1);
  }

  // prologue stage kt=0 -> buf0
#pragma unroll
  for (int i = 0; i < 4; ++i) {
    async16(&sA[0][sx[i]], aptr[i]);
    async16(&sB[0][sx[i]], bptr[i]);
  }

#pragma unroll 1
  for (int kt = 0; kt < 16; ++kt) {
    int cur = kt & 1;
    VMCNT0;  // K(kt) landed (own); barrier -> all waves
    BAR;
    SCHED0;
    if (kt < 15) {
#pragma unroll
      for (int i = 0; i < 4; ++i) {
        async16(&sA[cur ^ 1][sx[i]], aptr[i] + (kt + 1) * 64);
        async16(&sB[cur ^ 1][sx[i]], bptr[i] + (kt + 1) * 64);
      }
    }
#pragma unroll
    for (int kk = 0; kk < 2; ++kk) {
      bf16x8 af[4], bfr[4];
#pragma unroll
      for (int mf = 0; mf < 4; ++mf) {
        int row = wr * 64 + mf * 16 + cc;
        int colb = (kk * 64 + (g << 4)) ^ ((row & 7) << 4);
        af[mf] = *(const bf16x8*)&sA[cur][(row * 128 + colb) >> 1];
      }
#pragma unroll
      for (int nf = 0; nf < 4; ++nf) {
        int row = wc * 64 + nf * 16 + cc;
        int colb = (kk * 64 + (g << 4)) ^ ((row & 7) << 4);
        bfr[nf] = *(const bf16x8*)&sB[cur][(row * 128 + colb) >> 1];
      }
#pragma unroll
      for (int mf = 0; mf < 4; ++mf)
#pragma unroll
        for (int nf = 0; nf < 4; ++nf)
          acc[mf][nf] = __builtin_amdgcn_mfma_f32_16x16x32_bf16(af[mf], bfr[nf], acc[mf][nf], 0, 0, 0);
    }
  }

#pragma unroll
  for (int mf = 0; mf < 4; ++mf) {
#pragma unroll
    for (int nf = 0; nf < 4; ++nf) {
      int n = n0 + wc * 64 + nf * 16 + cc;
      float bval = bias[n];
      int h = n >> 6, d = n & 63;
#pragma unroll
      for (int r = 0; r < 4; ++r) {
        int m = m0 + wr * 64 + mf * 16 + g * 4 + r;
        int b = m >> 10, s = m & 1023;
        u16 o = f2bf(acc[mf][nf][r] + bval);
        if (which == 0)
          Qh[((((size_t)b * NUM_HEADS + h) * SEQ + s) << 6) + d] = o;
        else if (which == 1)
          Kh[((((size_t)b * NUM_HEADS + h) * SEQ + s) << 6) + d] = o;
        else
          Vt[(((size_t)b * NUM_HEADS + h) * 64 + d) * SEQ + s] = o;
      }
    }
  }
}

// ---------------- fused attention: 2-pass online softmax, K dbuf + prefetch ----------------
__global__ __launch_bounds__(256) void k_attn(
    const u16* __restrict__ Qh, const u16* __restrict__ Kh, const u16* __restrict__ Vt,
    const u16* __restrict__ adder, const int* __restrict__ flags,
    float* __restrict__ ctx, float* __restrict__ probs) {
  __shared__ u16 sK[2][128 * 64];  // 32 KB, dbuf
  __shared__ u16 sV[64 * 128];     // 16 KB
  __shared__ u16 sP[128 * 128];    // 32 KB, wave-local rows
  int ft = blockIdx.x, h = blockIdx.y, b = blockIdx.z;
  int f0 = ft * 128;
  int bh = b * NUM_HEADS + h;
  const u16* Qg = Qh + ((size_t)bh * SEQ + f0) * 64;
  const u16* Kg = Kh + (size_t)bh * SEQ * 64;
  const u16* Vg = Vt + (size_t)bh * 64 * SEQ;
  int tid = threadIdx.x, w = tid >> 6, lane = tid & 63;
  int g = lane >> 4, cc = lane & 15;
  const int fbase = w * 32;

  // hoist flags (avoid mid-loop loads that disturb vmcnt counting)
  int flgmask = 0;
#pragma unroll
  for (int tt = 0; tt < 8; ++tt)
    flgmask |= (flags[(b * 8 + ft) * 8 + tt] != 0) << tt;

  int sx[4];
  const u16* kbase[4];
  const u16* vbase[4];
#pragma unroll
  for (int i = 0; i < 4; ++i) {
    int ch = w * 4 + i;
    int x = ch * 1024 + lane * 16;
    sx[i] = ch * 512;
    int r7 = x >> 7;
    int c7 = (x & 127) ^ ((r7 & 7) << 4);
    kbase[i] = Kg + (size_t)r7 * 64 + (c7 >> 1);
    int r8 = x >> 8;
    int c8 = (x & 255) ^ ((r8 & 7) << 4);
    vbase[i] = Vg + (size_t)r8 * SEQ + (c8 >> 1);
  }

  // Q fragments -> registers (one-time, L2-resident)
  bf16x8 aq[2][2];
#pragma unroll
  for (int kk = 0; kk < 2; ++kk)
#pragma unroll
    for (int mf = 0; mf < 2; ++mf)
      aq[kk][mf] = *(const bf16x8*)&Qg[(size_t)(fbase + mf * 16 + cc) * 64 + kk * 32 + g * 8];

  float m_run[8], l_run[8];
#pragma unroll
  for (int i = 0; i < 8; ++i) { m_run[i] = -3.0e38f; l_run[i] = 0.0f; }

  // prologue: stage K0 -> buf0
#pragma unroll
  for (int i = 0; i < 4; ++i) async16(&sK[0][sx[i]], kbase[i]);

  // ---- pass 1: online (m,l) in log2 domain ----
#pragma unroll 1
  for (int tt = 0; tt < 8; ++tt) {
    int cur = tt & 1;
    VMCNT0;
    BAR;
    SCHED0;
    if (tt < 7) {
#pragma unroll
      for (int i = 0; i < 4; ++i)
        async16(&sK[cur ^ 1][sx[i]], kbase[i] + (tt + 1) * 8192);
    }
    f32x4 s[2][8] = {};
#pragma unroll
    for (int kk = 0; kk < 2; ++kk) {
      bf16x8 bk8[8];
#pragma unroll
      for (int nf = 0; nf < 8; ++nf) {
        int row = nf * 16 + cc;
        int colb = (kk * 64 + (g << 4)) ^ ((row & 7) << 4);
        bk8[nf] = *(const bf16x8*)&sK[cur][(row * 128 + colb) >> 1];
      }
#pragma unroll
      for (int mf = 0; mf < 2; ++mf)
#pragma unroll
        for (int nf = 0; nf < 8; ++nf)
          s[mf][nf] = __builtin_amdgcn_mfma_f32_16x16x32_bf16(aq[kk][mf], bk8[nf], s[mf][nf], 0, 0, 0);
    }
#pragma unroll
    for (int mf = 0; mf < 2; ++mf)
#pragma unroll
      for (int nf = 0; nf < 8; ++nf)
        s[mf][nf] = s[mf][nf] * C1;
    if ((flgmask >> tt) & 1) {
      for (int mf = 0; mf < 2; ++mf)
        for (int nf = 0; nf < 8; ++nf)
          for (int r = 0; r < 4; ++r) {
            int frow = f0 + fbase + mf * 16 + g * 4 + r;
            int tcol = tt * 128 + nf * 16 + cc;
            s[mf][nf][r] += bf2f(adder[((size_t)b * SEQ + frow) * SEQ + tcol]);
          }
    }
#pragma unroll
    for (int mf = 0; mf < 2; ++mf)
#pragma unroll
      for (int r = 0; r < 4; ++r) {
        float tmax = s[mf][0][r];
#pragma unroll
        for (int nf = 1; nf < 8; ++nf) tmax = fmaxf(tmax, s[mf][nf][r]);
        tmax = fmaxf(tmax, __shfl_xor(tmax, 1, 16));
        tmax = fmaxf(tmax, __shfl_xor(tmax, 2, 16));
        tmax = fmaxf(tmax, __shfl_xor(tmax, 4, 16));
        tmax = fmaxf(tmax, __shfl_xor(tmax, 8, 16));
        int idx = mf * 4 + r;
        float mnew = fmaxf(m_run[idx], tmax);
        float sum = 0.f;
#pragma unroll
        for (int nf = 0; nf < 8; ++nf) sum += exp2f(s[mf][nf][r] - mnew);
        sum += __shfl_xor(sum, 1, 16);
        sum += __shfl_xor(sum, 2, 16);
        sum += __shfl_xor(sum, 4, 16);
        sum += __shfl_xor(sum, 8, 16);
        l_run[idx] = l_run[idx] * exp2f(m_run[idx] - mnew) + sum;
        m_run[idx] = mnew;
      }
  }

  float inv_l[8];
#pragma unroll
  for (int i = 0; i < 8; ++i) inv_l[i] = 1.0f / l_run[i];

  f32x4 accO[2][4] = {};

  // re-prime K0 for pass 2 (sK[0] readers finished >=2 barriers ago)
#pragma unroll
  for (int i = 0; i < 4; ++i) async16(&sK[0][sx[i]], kbase[i]);

  // ---- pass 2: recompute S, write probs (coalesced via sP), accumulate ctx ----
#pragma unroll 1
  for (int tt = 0; tt < 8; ++tt) {
    int cur = tt & 1;
    VMCNT0;  // K(tt) landed (own) + residual stores drained
    BAR;
    SCHED0;
    // stage V(tt): hidden under QK^T + softmax
#pragma unroll
    for (int i = 0; i < 4; ++i) async16(&sV[sx[i]], vbase[i] + tt * 128);

    f32x4 s[2][8] = {};
#pragma unroll
    for (int kk = 0; kk < 2; ++kk) {
      bf16x8 bk8[8];
#pragma unroll
      for (int nf = 0; nf < 8; ++nf) {
        int row = nf * 16 + cc;
        int colb = (kk * 64 + (g << 4)) ^ ((row & 7) << 4);
        bk8[nf] = *(const bf16x8*)&sK[cur][(row * 128 + colb) >> 1];
      }
#pragma unroll
      for (int mf = 0; mf < 2; ++mf)
#pragma unroll
        for (int nf = 0; nf < 8; ++nf)
          s[mf][nf] = __builtin_amdgcn_mfma_f32_16x16x32_bf16(aq[kk][mf], bk8[nf], s[mf][nf], 0, 0, 0);
    }
#pragma unroll
    for (int mf = 0; mf < 2; ++mf)
#pragma unroll
      for (int nf = 0; nf < 8; ++nf)
        s[mf][nf] = s[mf][nf] * C1;
    if ((flgmask >> tt) & 1) {
      for (int mf = 0; mf < 2; ++mf)
        for (int nf = 0; nf < 8; ++nf)
          for (int r = 0; r < 4; ++r) {
            int frow = f0 + fbase + mf * 16 + g * 4 + r;
            int tcol = tt * 128 + nf * 16 + cc;
            s[mf][nf][r] += bf2f(adder[((size_t)b * SEQ + frow) * SEQ + tcol]);
          }
    }
    // p = 2^(s2-m) * inv_l ; write bf16 to wave-local sP
#pragma unroll
    for (int mf = 0; mf < 2; ++mf)
#pragma unroll
      for (int nf = 0; nf < 8; ++nf)
#pragma unroll
        for (int r = 0; r < 4; ++r) {
          int idx = mf * 4 + r;
          float p = exp2f(s[mf][nf][r] - m_run[idx]) * inv_l[idx];
          int frow = fbase + mf * 16 + g * 4 + r;
          int tcol = nf * 16 + cc;
          sP[(frow * 256 + ((tcol * 2) ^ ((frow & 7) << 4))) >> 1] = f2bf(p);
        }
    // coalesced probs store: read back own wave's 32 rows from sP (16 float4 stores)
#pragma unroll
    for (int sw = 0; sw < 8; ++sw) {
      int row = fbase + sw * 4 + (lane >> 4);
      int colb = ((lane & 15) * 16) ^ ((row & 7) << 4);
      u16x8 pv = *(const u16x8*)&sP[(row * 256 + colb) >> 1];
      float* dst = &probs[((size_t)bh * SEQ + f0 + row) * SEQ + tt * 128 + (lane & 15) * 8];
      f32x4 o0 = {bf2f(pv[0]), bf2f(pv[1]), bf2f(pv[2]), bf2f(pv[3])};
      f32x4 o1 = {bf2f(pv[4]), bf2f(pv[5]), bf2f(pv[6]), bf2f(pv[7])};
      *(f32x4*)dst = o0;
      *(f32x4*)(dst + 4) = o1;
    }
    // prefetch K(tt+1) now; stays in flight across the counted wait below
    if (tt < 7) {
#pragma unroll
      for (int i = 0; i < 4; ++i)
        async16(&sK[cur ^ 1][sx[i]], kbase[i] + (tt + 1) * 8192);
      VMCNT4;  // waits V(tt)+stores (in-order), leaves K(tt+1) in flight
    } else {
      VMCNT0;
    }
    BAR;  // all waves' V landed
    SCHED0;
#pragma unroll
    for (int ks = 0; ks < 4; ++ks) {
      bf16x8 ap[2], bv8[4];
#pragma unroll
      for (int mf = 0; mf < 2; ++mf) {
        int row = fbase + mf * 16 + cc;
        int colb = (ks * 64 + (g << 4)) ^ ((row & 7) << 4);
        ap[mf] = *(const bf16x8*)&sP[(row * 256 + colb) >> 1];
      }
#pragma unroll
      for (int nf = 0; nf < 4; ++nf) {
        int row = nf * 16 + cc;
        int colb = (ks * 64 + (g << 4)) ^ ((row & 7) << 4);
        bv8[nf] = *(const bf16x8*)&sV[(row * 256 + colb) >> 1];
      }
#pragma unroll
      for (int mf = 0; mf < 2; ++mf)
#pragma unroll
        for (int nf = 0; nf < 4; ++nf)
          accO[mf][nf] = __builtin_amdgcn_mfma_f32_16x16x32_bf16(ap[mf], bv8[nf], accO[mf][nf], 0, 0, 0);
    }
  }

#pragma unroll
  for (int mf = 0; mf < 2; ++mf)
#pragma unroll
    for (int nf = 0; nf < 4; ++nf)
#pragma unroll
      for (int r = 0; r < 4; ++r) {
        int frow = fbase + mf * 16 + g * 4 + r;
        int d = nf * 16 + cc;
        ctx[((size_t)b * SEQ + f0 + frow) * HIDDEN + h * 64 + d] = accO[mf][nf][r];
      }
}

extern "C" void kernel_launch(void* const* d_in, const int* in_sizes, int n_in,
                              void* d_out, int out_size, void* d_ws, size_t ws_size,
                              hipStream_t stream) {
  const float* from = (const float*)d_in[0];
  const float* to   = (const float*)d_in[1];
  const float* mask = (const float*)d_in[2];
  const float* Wq   = (const float*)d_in[3];
  const float* bq   = (const float*)d_in[4];
  const float* Wk   = (const float*)d_in[5];
  const float* bk   = (const float*)d_in[6];
  const float* Wv   = (const float*)d_in[7];
  const float* bv   = (const float*)d_in[8];

  char* ws = (char*)d_ws;
  u16* Af    = (u16*)(ws);
  u16* At    = (u16*)(ws + 8388608);
  u16* Wt    = (u16*)(ws + 16777216);
  u16* adder = (u16*)(ws + 23068672);
  int* flags = (int*)(ws + 31457280);
  u16* Qh    = (u16*)(ws + 31458304);
  u16* Kh    = (u16*)(ws + 39846912);
  u16* Vt    = (u16*)(ws + 48235520);

  float* ctx = (float*)d_out;
  float* probs = ctx + (size_t)BATCH * SEQ * HIDDEN;

  k_cvt<<<dim3(2048, 1, 2), 256, 0, stream>>>(from, Af, to, At, 524288);
  k_wtrans<<<dim3(16, 16, 3), 256, 0, stream>>>(Wq, Wk, Wv, Wt);
  k_mask<<<dim3(8, 8, 4), 256, 0, stream>>>(mask, adder, flags);
  k_gemm<<<dim3(8, 32, 3), 256, 0, stream>>>(Af, At, Wt, bq, bk, bv, Qh, Kh, Vt);
  k_attn<<<dim3(8, 16, 4), 256, 0, stream>>>(Qh, Kh, Vt, adder, flags, ctx, probs);
}

// Round 3
// 229.300 us; speedup vs baseline: 1.0223x; 1.0223x over previous
//
#include <hip/hip_runtime.h>

typedef unsigned short u16;
typedef __bf16 bf16x8 __attribute__((ext_vector_type(8)));
typedef float f32x4 __attribute__((ext_vector_type(4)));
typedef u16 u16x8 __attribute__((ext_vector_type(8)));
typedef u16 u16x4 __attribute__((ext_vector_type(4)));

#define NUM_HEADS 16
#define HIDDEN 1024
#define BATCH 4
#define SEQ 1024
// 0.125 * log2(e): fold the 1/sqrt(64) scale and the exp->exp2 conversion
#define C1 0.1803368809109783f
#define LOG2E 1.4426950408889634f

#define VMCNT0 asm volatile("s_waitcnt vmcnt(0)" ::: "memory")
#define VMCNT4 asm volatile("s_waitcnt vmcnt(4)" ::: "memory")
#define BAR __builtin_amdgcn_s_barrier()
#define SCHED0 __builtin_amdgcn_sched_barrier(0)

static __device__ __forceinline__ u16 f2bf(float x) {
  unsigned u = __float_as_uint(x);
  u = u + 0x7FFFu + ((u >> 16) & 1u);
  return (u16)(u >> 16);
}
static __device__ __forceinline__ float bf2f(u16 b) {
  return __uint_as_float(((unsigned)b) << 16);
}
static __device__ __forceinline__ void async16(u16* lds, const u16* g) {
  __builtin_amdgcn_global_load_lds(
      (const __attribute__((address_space(1))) void*)g,
      (__attribute__((address_space(3))) void*)lds, 16, 0, 0);
}

// ---------------- prep: fp32 -> bf16 (x8 per thread), z selects tensor ----------------
__global__ void k_cvt(const float* __restrict__ in0, u16* __restrict__ out0,
                      const float* __restrict__ in1, u16* __restrict__ out1, int n8) {
  int i = blockIdx.x * 256 + threadIdx.x;
  if (i >= n8) return;
  const float* in = blockIdx.z ? in1 : in0;
  u16* out = blockIdx.z ? out1 : out0;
  float4 a = ((const float4*)in)[i * 2];
  float4 b = ((const float4*)in)[i * 2 + 1];
  u16x8 v;
  v[0] = f2bf(a.x); v[1] = f2bf(a.y); v[2] = f2bf(a.z); v[3] = f2bf(a.w);
  v[4] = f2bf(b.x); v[5] = f2bf(b.y); v[6] = f2bf(b.z); v[7] = f2bf(b.w);
  *(u16x8*)&out[(size_t)i * 8] = v;
}

// ---------------- prep: W [K][N] fp32 -> Wt [N][K] bf16 ----------------
__global__ void k_wtrans(const float* __restrict__ Wq, const float* __restrict__ Wk,
                         const float* __restrict__ Wv, u16* __restrict__ Wt) {
  __shared__ float tile[64][65];
  const float* W = (blockIdx.z == 0) ? Wq : (blockIdx.z == 1) ? Wk : Wv;
  u16* out = Wt + (size_t)blockIdx.z * HIDDEN * HIDDEN;
  int k0 = blockIdx.y * 64, n0 = blockIdx.x * 64;
  int tid = threadIdx.x;
  int r = tid >> 6, c = tid & 63;
#pragma unroll
  for (int i = 0; i < 16; ++i)
    tile[i * 4 + r][c] = W[(size_t)(k0 + i * 4 + r) * HIDDEN + n0 + c];
  __syncthreads();
#pragma unroll
  for (int i = 0; i < 16; ++i)
    out[(size_t)(n0 + i * 4 + r) * HIDDEN + k0 + c] = f2bf(tile[c][i * 4 + r]);
}

// ---------------- prep: mask -> log2-domain bf16 adder + tile flags ----------------
// All-ones tiles (the common case): write only the flag, skip the adder write.
__global__ void k_mask(const float* __restrict__ mask, u16* __restrict__ adder,
                       int* __restrict__ flags) {
  int tt = blockIdx.x, ft = blockIdx.y, b = blockIdx.z;
  int tid = threadIdx.x;
  __shared__ int sflag;
  if (tid == 0) sflag = 0;
  __syncthreads();
  size_t base = ((size_t)b * SEQ + ft * 128) * SEQ + tt * 128;
  int any = 0;
#pragma unroll
  for (int i = 0; i < 16; ++i) {
    int idx = i * 256 + tid;           // 4096 float4s per 128x128 tile
    int r = idx >> 5, c4 = idx & 31;   // 32 float4 per row
    float4 v = *(const float4*)&mask[base + (size_t)r * SEQ + c4 * 4];
    any |= (v.x != 1.0f) | (v.y != 1.0f) | (v.z != 1.0f) | (v.w != 1.0f);
  }
  if (any) sflag = 1;
  __syncthreads();
  if (sflag) {
#pragma unroll
    for (int i = 0; i < 16; ++i) {
      int idx = i * 256 + tid;
      int r = idx >> 5, c4 = idx & 31;
      float4 v = *(const float4*)&mask[base + (size_t)r * SEQ + c4 * 4];
      u16x4 o;
      o[0] = f2bf((1.0f - v.x) * -10000.0f * LOG2E);
      o[1] = f2bf((1.0f - v.y) * -10000.0f * LOG2E);
      o[2] = f2bf((1.0f - v.z) * -10000.0f * LOG2E);
      o[3] = f2bf((1.0f - v.w) * -10000.0f * LOG2E);
      *(u16x4*)&adder[base + (size_t)r * SEQ + c4 * 4] = o;
    }
  }
  if (tid == 0) flags[(b * 8 + ft) * 8 + tt] = sflag;
}

// ---------------- QKV GEMM: 128x128 tile, BK=64, single-buffer (r1 structure) ----------------
__global__ __launch_bounds__(256) void k_gemm(
    const u16* __restrict__ Af, const u16* __restrict__ At,
    const u16* __restrict__ Wt,
    const float* __restrict__ bq, const float* __restrict__ bk, const float* __restrict__ bv,
    u16* __restrict__ Qh, u16* __restrict__ Kh, u16* __restrict__ Vt) {
  __shared__ u16 sA[128 * 64];
  __shared__ u16 sB[128 * 64];
  int which = blockIdx.z;
  const u16* A = (which == 0) ? Af : At;
  const u16* B = Wt + (size_t)which * HIDDEN * HIDDEN;
  const float* bias = (which == 0) ? bq : (which == 1) ? bk : bv;
  int m0 = blockIdx.y * 128, n0 = blockIdx.x * 128;
  int tid = threadIdx.x, w = tid >> 6, lane = tid & 63;
  int wr = w >> 1, wc = w & 1;
  int g = lane >> 4, cc = lane & 15;

  f32x4 acc[4][4] = {};

  int sx[4], srow[4], scol[4];
#pragma unroll
  for (int i = 0; i < 4; ++i) {
    int ch = w * 4 + i;
    int x = ch * 1024 + lane * 16;
    int row = x >> 7;
    int colb = (x & 127) ^ ((row & 7) << 4);  // pre-swizzled source
    sx[i] = ch * 512;
    srow[i] = row;
    scol[i] = colb >> 1;
  }

  for (int kt = 0; kt < HIDDEN / 64; ++kt) {
    __syncthreads();
#pragma unroll
    for (int i = 0; i < 4; ++i) {
      async16(&sA[sx[i]], A + (size_t)(m0 + srow[i]) * HIDDEN + kt * 64 + scol[i]);
      async16(&sB[sx[i]], B + (size_t)(n0 + srow[i]) * HIDDEN + kt * 64 + scol[i]);
    }
    asm volatile("s_waitcnt vmcnt(0)" ::: "memory");
    __syncthreads();
#pragma unroll
    for (int kk = 0; kk < 2; ++kk) {
      bf16x8 af[4], bfr[4];
#pragma unroll
      for (int mf = 0; mf < 4; ++mf) {
        int row = wr * 64 + mf * 16 + cc;
        int colb = (kk * 64 + (g << 4)) ^ ((row & 7) << 4);
        af[mf] = *(const bf16x8*)&sA[(row * 128 + colb) >> 1];
      }
#pragma unroll
      for (int nf = 0; nf < 4; ++nf) {
        int row = wc * 64 + nf * 16 + cc;
        int colb = (kk * 64 + (g << 4)) ^ ((row & 7) << 4);
        bfr[nf] = *(const bf16x8*)&sB[(row * 128 + colb) >> 1];
      }
#pragma unroll
      for (int mf = 0; mf < 4; ++mf)
#pragma unroll
        for (int nf = 0; nf < 4; ++nf)
          acc[mf][nf] = __builtin_amdgcn_mfma_f32_16x16x32_bf16(af[mf], bfr[nf], acc[mf][nf], 0, 0, 0);
    }
  }

#pragma unroll
  for (int mf = 0; mf < 4; ++mf) {
#pragma unroll
    for (int nf = 0; nf < 4; ++nf) {
      int n = n0 + wc * 64 + nf * 16 + cc;
      float bval = bias[n];
      int h = n >> 6, d = n & 63;
#pragma unroll
      for (int r = 0; r < 4; ++r) {
        int m = m0 + wr * 64 + mf * 16 + g * 4 + r;
        int b = m >> 10, s = m & 1023;
        u16 o = f2bf(acc[mf][nf][r] + bval);
        if (which == 0)
          Qh[((((size_t)b * NUM_HEADS + h) * SEQ + s) << 6) + d] = o;
        else if (which == 1)
          Kh[((((size_t)b * NUM_HEADS + h) * SEQ + s) << 6) + d] = o;
        else
          Vt[(((size_t)b * NUM_HEADS + h) * 64 + d) * SEQ + s] = o;
      }
    }
  }
}

// ---------------- fused attention: 2-pass online softmax, K dbuf + counted waits ----------------
__global__ __launch_bounds__(256) void k_attn(
    const u16* __restrict__ Qh, const u16* __restrict__ Kh, const u16* __restrict__ Vt,
    const u16* __restrict__ adder, const int* __restrict__ flags,
    float* __restrict__ ctx, float* __restrict__ probs) {
  __shared__ u16 sK[2][128 * 64];  // 32 KB, dbuf
  __shared__ u16 sV[64 * 128];     // 16 KB
  __shared__ u16 sP[128 * 128];    // 32 KB, wave-local rows
  // XCD-chunked swizzle: 512 blocks, 8 XCDs, 64 logical blocks per XCD.
  // XCD j gets logical j*64..j*64+63 => 8 consecutive (b,h) pairs (K/V 2MB L2-resident).
  int wg = blockIdx.x;
  int logical = (wg & 7) * 64 + (wg >> 3);
  int ft = logical & 7, h = (logical >> 3) & 15, b = logical >> 7;
  int f0 = ft * 128;
  int bh = b * NUM_HEADS + h;
  const u16* Qg = Qh + ((size_t)bh * SEQ + f0) * 64;
  const u16* Kg = Kh + (size_t)bh * SEQ * 64;
  const u16* Vg = Vt + (size_t)bh * 64 * SEQ;
  int tid = threadIdx.x, w = tid >> 6, lane = tid & 63;
  int g = lane >> 4, cc = lane & 15;
  const int fbase = w * 32;

  // hoist flags (avoid mid-loop loads that disturb vmcnt counting)
  int flgmask = 0;
#pragma unroll
  for (int tt = 0; tt < 8; ++tt)
    flgmask |= (flags[(b * 8 + ft) * 8 + tt] != 0) << tt;

  int sx[4];
  const u16* kbase[4];
  const u16* vbase[4];
#pragma unroll
  for (int i = 0; i < 4; ++i) {
    int ch = w * 4 + i;
    int x = ch * 1024 + lane * 16;
    sx[i] = ch * 512;
    int r7 = x >> 7;
    int c7 = (x & 127) ^ ((r7 & 7) << 4);
    kbase[i] = Kg + (size_t)r7 * 64 + (c7 >> 1);
    int r8 = x >> 8;
    int c8 = (x & 255) ^ ((r8 & 7) << 4);
    vbase[i] = Vg + (size_t)r8 * SEQ + (c8 >> 1);
  }

  // Q fragments -> registers (one-time, L2-resident)
  bf16x8 aq[2][2];
#pragma unroll
  for (int kk = 0; kk < 2; ++kk)
#pragma unroll
    for (int mf = 0; mf < 2; ++mf)
      aq[kk][mf] = *(const bf16x8*)&Qg[(size_t)(fbase + mf * 16 + cc) * 64 + kk * 32 + g * 8];

  float m_run[8], l_run[8];
#pragma unroll
  for (int i = 0; i < 8; ++i) { m_run[i] = -3.0e38f; l_run[i] = 0.0f; }

  // prologue: stage K0 -> buf0
#pragma unroll
  for (int i = 0; i < 4; ++i) async16(&sK[0][sx[i]], kbase[i]);

  // ---- pass 1: online (m,l) in log2 domain ----
#pragma unroll 1
  for (int tt = 0; tt < 8; ++tt) {
    int cur = tt & 1;
    VMCNT0;
    BAR;
    SCHED0;
    if (tt < 7) {
#pragma unroll
      for (int i = 0; i < 4; ++i)
        async16(&sK[cur ^ 1][sx[i]], kbase[i] + (tt + 1) * 8192);
    }
    f32x4 s[2][8] = {};
#pragma unroll
    for (int kk = 0; kk < 2; ++kk) {
      bf16x8 bk8[8];
#pragma unroll
      for (int nf = 0; nf < 8; ++nf) {
        int row = nf * 16 + cc;
        int colb = (kk * 64 + (g << 4)) ^ ((row & 7) << 4);
        bk8[nf] = *(const bf16x8*)&sK[cur][(row * 128 + colb) >> 1];
      }
#pragma unroll
      for (int mf = 0; mf < 2; ++mf)
#pragma unroll
        for (int nf = 0; nf < 8; ++nf)
          s[mf][nf] = __builtin_amdgcn_mfma_f32_16x16x32_bf16(aq[kk][mf], bk8[nf], s[mf][nf], 0, 0, 0);
    }
#pragma unroll
    for (int mf = 0; mf < 2; ++mf)
#pragma unroll
      for (int nf = 0; nf < 8; ++nf)
        s[mf][nf] = s[mf][nf] * C1;
    if ((flgmask >> tt) & 1) {
      for (int mf = 0; mf < 2; ++mf)
        for (int nf = 0; nf < 8; ++nf)
          for (int r = 0; r < 4; ++r) {
            int frow = f0 + fbase + mf * 16 + g * 4 + r;
            int tcol = tt * 128 + nf * 16 + cc;
            s[mf][nf][r] += bf2f(adder[((size_t)b * SEQ + frow) * SEQ + tcol]);
          }
    }
#pragma unroll
    for (int mf = 0; mf < 2; ++mf)
#pragma unroll
      for (int r = 0; r < 4; ++r) {
        float tmax = s[mf][0][r];
#pragma unroll
        for (int nf = 1; nf < 8; ++nf) tmax = fmaxf(tmax, s[mf][nf][r]);
        tmax = fmaxf(tmax, __shfl_xor(tmax, 1, 16));
        tmax = fmaxf(tmax, __shfl_xor(tmax, 2, 16));
        tmax = fmaxf(tmax, __shfl_xor(tmax, 4, 16));
        tmax = fmaxf(tmax, __shfl_xor(tmax, 8, 16));
        int idx = mf * 4 + r;
        float mnew = fmaxf(m_run[idx], tmax);
        float sum = 0.f;
#pragma unroll
        for (int nf = 0; nf < 8; ++nf) sum += exp2f(s[mf][nf][r] - mnew);
        sum += __shfl_xor(sum, 1, 16);
        sum += __shfl_xor(sum, 2, 16);
        sum += __shfl_xor(sum, 4, 16);
        sum += __shfl_xor(sum, 8, 16);
        l_run[idx] = l_run[idx] * exp2f(m_run[idx] - mnew) + sum;
        m_run[idx] = mnew;
      }
  }

  float inv_l[8];
#pragma unroll
  for (int i = 0; i < 8; ++i) inv_l[i] = 1.0f / l_run[i];

  f32x4 accO[2][4] = {};

  // re-prime K0 for pass 2 (sK[0] readers finished >=2 barriers ago)
#pragma unroll
  for (int i = 0; i < 4; ++i) async16(&sK[0][sx[i]], kbase[i]);

  // ---- pass 2: recompute S, write probs (coalesced via sP), accumulate ctx ----
#pragma unroll 1
  for (int tt = 0; tt < 8; ++tt) {
    int cur = tt & 1;
    VMCNT0;  // K(tt) landed (own) + residual stores drained
    BAR;
    SCHED0;
    // stage V(tt): hidden under QK^T + softmax
#pragma unroll
    for (int i = 0; i < 4; ++i) async16(&sV[sx[i]], vbase[i] + tt * 128);

    f32x4 s[2][8] = {};
#pragma unroll
    for (int kk = 0; kk < 2; ++kk) {
      bf16x8 bk8[8];
#pragma unroll
      for (int nf = 0; nf < 8; ++nf) {
        int row = nf * 16 + cc;
        int colb = (kk * 64 + (g << 4)) ^ ((row & 7) << 4);
        bk8[nf] = *(const bf16x8*)&sK[cur][(row * 128 + colb) >> 1];
      }
#pragma unroll
      for (int mf = 0; mf < 2; ++mf)
#pragma unroll
        for (int nf = 0; nf < 8; ++nf)
          s[mf][nf] = __builtin_amdgcn_mfma_f32_16x16x32_bf16(aq[kk][mf], bk8[nf], s[mf][nf], 0, 0, 0);
    }
#pragma unroll
    for (int mf = 0; mf < 2; ++mf)
#pragma unroll
      for (int nf = 0; nf < 8; ++nf)
        s[mf][nf] = s[mf][nf] * C1;
    if ((flgmask >> tt) & 1) {
      for (int mf = 0; mf < 2; ++mf)
        for (int nf = 0; nf < 8; ++nf)
          for (int r = 0; r < 4; ++r) {
            int frow = f0 + fbase + mf * 16 + g * 4 + r;
            int tcol = tt * 128 + nf * 16 + cc;
            s[mf][nf][r] += bf2f(adder[((size_t)b * SEQ + frow) * SEQ + tcol]);
          }
    }
    // p = 2^(s2-m) * inv_l ; write bf16 to wave-local sP
#pragma unroll
    for (int mf = 0; mf < 2; ++mf)
#pragma unroll
      for (int nf = 0; nf < 8; ++nf)
#pragma unroll
        for (int r = 0; r < 4; ++r) {
          int idx = mf * 4 + r;
          float p = exp2f(s[mf][nf][r] - m_run[idx]) * inv_l[idx];
          int frow = fbase + mf * 16 + g * 4 + r;
          int tcol = nf * 16 + cc;
          sP[(frow * 256 + ((tcol * 2) ^ ((frow & 7) << 4))) >> 1] = f2bf(p);
        }
    // coalesced probs store: read back own wave's 32 rows from sP (16 float4 stores)
#pragma unroll
    for (int sw = 0; sw < 8; ++sw) {
      int row = fbase + sw * 4 + (lane >> 4);
      int colb = ((lane & 15) * 16) ^ ((row & 7) << 4);
      u16x8 pv = *(const u16x8*)&sP[(row * 256 + colb) >> 1];
      float* dst = &probs[((size_t)bh * SEQ + f0 + row) * SEQ + tt * 128 + (lane & 15) * 8];
      f32x4 o0 = {bf2f(pv[0]), bf2f(pv[1]), bf2f(pv[2]), bf2f(pv[3])};
      f32x4 o1 = {bf2f(pv[4]), bf2f(pv[5]), bf2f(pv[6]), bf2f(pv[7])};
      *(f32x4*)dst = o0;
      *(f32x4*)(dst + 4) = o1;
    }
    // prefetch K(tt+1) now; stays in flight across the counted wait below.
    // Safety: V-loads are the oldest in-flight LOADS; loads retire in order, so
    // any post-wait residue is K and/or stores — V is guaranteed landed.
    if (tt < 7) {
#pragma unroll
      for (int i = 0; i < 4; ++i)
        async16(&sK[cur ^ 1][sx[i]], kbase[i] + (tt + 1) * 8192);
      VMCNT4;  // waits V(tt)+stores, leaves K(tt+1) in flight
    } else {
      VMCNT0;
    }
    BAR;  // all waves' V landed
    SCHED0;
#pragma unroll
    for (int ks = 0; ks < 4; ++ks) {
      bf16x8 ap[2], bv8[4];
#pragma unroll
      for (int mf = 0; mf < 2; ++mf) {
        int row = fbase + mf * 16 + cc;
        int colb = (ks * 64 + (g << 4)) ^ ((row & 7) << 4);
        ap[mf] = *(const bf16x8*)&sP[(row * 256 + colb) >> 1];
      }
#pragma unroll
      for (int nf = 0; nf < 4; ++nf) {
        int row = nf * 16 + cc;
        int colb = (ks * 64 + (g << 4)) ^ ((row & 7) << 4);
        bv8[nf] = *(const bf16x8*)&sV[(row * 256 + colb) >> 1];
      }
#pragma unroll
      for (int mf = 0; mf < 2; ++mf)
#pragma unroll
        for (int nf = 0; nf < 4; ++nf)
          accO[mf][nf] = __builtin_amdgcn_mfma_f32_16x16x32_bf16(ap[mf], bv8[nf], accO[mf][nf], 0, 0, 0);
    }
  }

#pragma unroll
  for (int mf = 0; mf < 2; ++mf)
#pragma unroll
    for (int nf = 0; nf < 4; ++nf)
#pragma unroll
      for (int r = 0; r < 4; ++r) {
        int frow = fbase + mf * 16 + g * 4 + r;
        int d = nf * 16 + cc;
        ctx[((size_t)b * SEQ + f0 + frow) * HIDDEN + h * 64 + d] = accO[mf][nf][r];
      }
}

extern "C" void kernel_launch(void* const* d_in, const int* in_sizes, int n_in,
                              void* d_out, int out_size, void* d_ws, size_t ws_size,
                              hipStream_t stream) {
  const float* from = (const float*)d_in[0];
  const float* to   = (const float*)d_in[1];
  const float* mask = (const float*)d_in[2];
  const float* Wq   = (const float*)d_in[3];
  const float* bq   = (const float*)d_in[4];
  const float* Wk   = (const float*)d_in[5];
  const float* bk   = (const float*)d_in[6];
  const float* Wv   = (const float*)d_in[7];
  const float* bv   = (const float*)d_in[8];

  char* ws = (char*)d_ws;
  u16* Af    = (u16*)(ws);
  u16* At    = (u16*)(ws + 8388608);
  u16* Wt    = (u16*)(ws + 16777216);
  u16* adder = (u16*)(ws + 23068672);
  int* flags = (int*)(ws + 31457280);
  u16* Qh    = (u16*)(ws + 31458304);
  u16* Kh    = (u16*)(ws + 39846912);
  u16* Vt    = (u16*)(ws + 48235520);

  float* ctx = (float*)d_out;
  float* probs = ctx + (size_t)BATCH * SEQ * HIDDEN;

  k_cvt<<<dim3(2048, 1, 2), 256, 0, stream>>>(from, Af, to, At, 524288);
  k_wtrans<<<dim3(16, 16, 3), 256, 0, stream>>>(Wq, Wk, Wv, Wt);
  k_mask<<<dim3(8, 8, 4), 256, 0, stream>>>(mask, adder, flags);
  k_gemm<<<dim3(8, 32, 3), 256, 0, stream>>>(Af, At, Wt, bq, bk, bv, Qh, Kh, Vt);
  k_attn<<<512, 256, 0, stream>>>(Qh, Kh, Vt, adder, flags, ctx, probs);
}

// Round 4
// 229.206 us; speedup vs baseline: 1.0227x; 1.0004x over previous
//
#include <hip/hip_runtime.h>

typedef unsigned short u16;
typedef __bf16 bf16x8 __attribute__((ext_vector_type(8)));
typedef float f32x4 __attribute__((ext_vector_type(4)));
typedef u16 u16x8 __attribute__((ext_vector_type(8)));
typedef u16 u16x4 __attribute__((ext_vector_type(4)));

#define NUM_HEADS 16
#define HIDDEN 1024
#define BATCH 4
#define SEQ 1024
// 0.125 * log2(e): fold the 1/sqrt(64) scale and the exp->exp2 conversion
#define C1 0.1803368809109783f
#define LOG2E 1.4426950408889634f

#define VMCNT0 asm volatile("s_waitcnt vmcnt(0)" ::: "memory")
#define VMCNT4 asm volatile("s_waitcnt vmcnt(4)" ::: "memory")
#define BAR __builtin_amdgcn_s_barrier()
#define SCHED0 __builtin_amdgcn_sched_barrier(0)

static __device__ __forceinline__ u16 f2bf(float x) {
  unsigned u = __float_as_uint(x);
  u = u + 0x7FFFu + ((u >> 16) & 1u);
  return (u16)(u >> 16);
}
static __device__ __forceinline__ float bf2f(u16 b) {
  return __uint_as_float(((unsigned)b) << 16);
}
static __device__ __forceinline__ void async16(u16* lds, const u16* g) {
  __builtin_amdgcn_global_load_lds(
      (const __attribute__((address_space(1))) void*)g,
      (__attribute__((address_space(3))) void*)lds, 16, 0, 0);
}

// ---------------- prep: fp32 -> bf16 (x8 per thread), z selects tensor ----------------
__global__ void k_cvt(const float* __restrict__ in0, u16* __restrict__ out0,
                      const float* __restrict__ in1, u16* __restrict__ out1, int n8) {
  int i = blockIdx.x * 256 + threadIdx.x;
  if (i >= n8) return;
  const float* in = blockIdx.z ? in1 : in0;
  u16* out = blockIdx.z ? out1 : out0;
  float4 a = ((const float4*)in)[i * 2];
  float4 b = ((const float4*)in)[i * 2 + 1];
  u16x8 v;
  v[0] = f2bf(a.x); v[1] = f2bf(a.y); v[2] = f2bf(a.z); v[3] = f2bf(a.w);
  v[4] = f2bf(b.x); v[5] = f2bf(b.y); v[6] = f2bf(b.z); v[7] = f2bf(b.w);
  *(u16x8*)&out[(size_t)i * 8] = v;
}

// ---------------- prep: W [K][N] fp32 -> Wt [N][K] bf16 ----------------
__global__ void k_wtrans(const float* __restrict__ Wq, const float* __restrict__ Wk,
                         const float* __restrict__ Wv, u16* __restrict__ Wt) {
  __shared__ float tile[64][65];
  const float* W = (blockIdx.z == 0) ? Wq : (blockIdx.z == 1) ? Wk : Wv;
  u16* out = Wt + (size_t)blockIdx.z * HIDDEN * HIDDEN;
  int k0 = blockIdx.y * 64, n0 = blockIdx.x * 64;
  int tid = threadIdx.x;
  int r = tid >> 6, c = tid & 63;
#pragma unroll
  for (int i = 0; i < 16; ++i)
    tile[i * 4 + r][c] = W[(size_t)(k0 + i * 4 + r) * HIDDEN + n0 + c];
  __syncthreads();
#pragma unroll
  for (int i = 0; i < 16; ++i)
    out[(size_t)(n0 + i * 4 + r) * HIDDEN + k0 + c] = f2bf(tile[c][i * 4 + r]);
}

// ---------------- prep: mask -> log2-domain bf16 adder + tile flags ----------------
// All-ones tiles (the common case): write only the flag, skip the adder write.
__global__ void k_mask(const float* __restrict__ mask, u16* __restrict__ adder,
                       int* __restrict__ flags) {
  int tt = blockIdx.x, ft = blockIdx.y, b = blockIdx.z;
  int tid = threadIdx.x;
  __shared__ int sflag;
  if (tid == 0) sflag = 0;
  __syncthreads();
  size_t base = ((size_t)b * SEQ + ft * 128) * SEQ + tt * 128;
  int any = 0;
#pragma unroll
  for (int i = 0; i < 16; ++i) {
    int idx = i * 256 + tid;           // 4096 float4s per 128x128 tile
    int r = idx >> 5, c4 = idx & 31;   // 32 float4 per row
    float4 v = *(const float4*)&mask[base + (size_t)r * SEQ + c4 * 4];
    any |= (v.x != 1.0f) | (v.y != 1.0f) | (v.z != 1.0f) | (v.w != 1.0f);
  }
  if (any) sflag = 1;
  __syncthreads();
  if (sflag) {
#pragma unroll
    for (int i = 0; i < 16; ++i) {
      int idx = i * 256 + tid;
      int r = idx >> 5, c4 = idx & 31;
      float4 v = *(const float4*)&mask[base + (size_t)r * SEQ + c4 * 4];
      u16x4 o;
      o[0] = f2bf((1.0f - v.x) * -10000.0f * LOG2E);
      o[1] = f2bf((1.0f - v.y) * -10000.0f * LOG2E);
      o[2] = f2bf((1.0f - v.z) * -10000.0f * LOG2E);
      o[3] = f2bf((1.0f - v.w) * -10000.0f * LOG2E);
      *(u16x4*)&adder[base + (size_t)r * SEQ + c4 * 4] = o;
    }
  }
  if (tid == 0) flags[(b * 8 + ft) * 8 + tt] = sflag;
}

// ---------------- QKV GEMM: 128x128 tile, BK=64, single-buffer (r1 structure) ----------------
__global__ __launch_bounds__(256) void k_gemm(
    const u16* __restrict__ Af, const u16* __restrict__ At,
    const u16* __restrict__ Wt,
    const float* __restrict__ bq, const float* __restrict__ bk, const float* __restrict__ bv,
    u16* __restrict__ Qh, u16* __restrict__ Kh, u16* __restrict__ Vt) {
  __shared__ u16 sA[128 * 64];
  __shared__ u16 sB[128 * 64];
  int which = blockIdx.z;
  const u16* A = (which == 0) ? Af : At;
  const u16* B = Wt + (size_t)which * HIDDEN * HIDDEN;
  const float* bias = (which == 0) ? bq : (which == 1) ? bk : bv;
  int m0 = blockIdx.y * 128, n0 = blockIdx.x * 128;
  int tid = threadIdx.x, w = tid >> 6, lane = tid & 63;
  int wr = w >> 1, wc = w & 1;
  int g = lane >> 4, cc = lane & 15;

  f32x4 acc[4][4] = {};

  int sx[4], srow[4], scol[4];
#pragma unroll
  for (int i = 0; i < 4; ++i) {
    int ch = w * 4 + i;
    int x = ch * 1024 + lane * 16;
    int row = x >> 7;
    int colb = (x & 127) ^ ((row & 7) << 4);  // pre-swizzled source
    sx[i] = ch * 512;
    srow[i] = row;
    scol[i] = colb >> 1;
  }

  for (int kt = 0; kt < HIDDEN / 64; ++kt) {
    __syncthreads();
#pragma unroll
    for (int i = 0; i < 4; ++i) {
      async16(&sA[sx[i]], A + (size_t)(m0 + srow[i]) * HIDDEN + kt * 64 + scol[i]);
      async16(&sB[sx[i]], B + (size_t)(n0 + srow[i]) * HIDDEN + kt * 64 + scol[i]);
    }
    asm volatile("s_waitcnt vmcnt(0)" ::: "memory");
    __syncthreads();
#pragma unroll
    for (int kk = 0; kk < 2; ++kk) {
      bf16x8 af[4], bfr[4];
#pragma unroll
      for (int mf = 0; mf < 4; ++mf) {
        int row = wr * 64 + mf * 16 + cc;
        int colb = (kk * 64 + (g << 4)) ^ ((row & 7) << 4);
        af[mf] = *(const bf16x8*)&sA[(row * 128 + colb) >> 1];
      }
#pragma unroll
      for (int nf = 0; nf < 4; ++nf) {
        int row = wc * 64 + nf * 16 + cc;
        int colb = (kk * 64 + (g << 4)) ^ ((row & 7) << 4);
        bfr[nf] = *(const bf16x8*)&sB[(row * 128 + colb) >> 1];
      }
#pragma unroll
      for (int mf = 0; mf < 4; ++mf)
#pragma unroll
        for (int nf = 0; nf < 4; ++nf)
          acc[mf][nf] = __builtin_amdgcn_mfma_f32_16x16x32_bf16(af[mf], bfr[nf], acc[mf][nf], 0, 0, 0);
    }
  }

#pragma unroll
  for (int mf = 0; mf < 4; ++mf) {
#pragma unroll
    for (int nf = 0; nf < 4; ++nf) {
      int n = n0 + wc * 64 + nf * 16 + cc;
      float bval = bias[n];
      int h = n >> 6, d = n & 63;
#pragma unroll
      for (int r = 0; r < 4; ++r) {
        int m = m0 + wr * 64 + mf * 16 + g * 4 + r;
        int b = m >> 10, s = m & 1023;
        u16 o = f2bf(acc[mf][nf][r] + bval);
        if (which == 0)
          Qh[((((size_t)b * NUM_HEADS + h) * SEQ + s) << 6) + d] = o;
        else if (which == 1)
          Kh[((((size_t)b * NUM_HEADS + h) * SEQ + s) << 6) + d] = o;
        else
          Vt[(((size_t)b * NUM_HEADS + h) * 64 + d) * SEQ + s] = o;
      }
    }
  }
}

// ---------------- fused attention: 2-pass online softmax ----------------
// Pass-2 schedule: waits never include stores; V hides under QK^T+softmax;
// K(tt+1) hides under softmax+probs+PV; probs stores drain under PV + next QK^T.
__global__ __launch_bounds__(256) void k_attn(
    const u16* __restrict__ Qh, const u16* __restrict__ Kh, const u16* __restrict__ Vt,
    const u16* __restrict__ adder, const int* __restrict__ flags,
    float* __restrict__ ctx, float* __restrict__ probs) {
  __shared__ u16 sK[2][128 * 64];  // 32 KB, dbuf
  __shared__ u16 sV[64 * 128];     // 16 KB
  __shared__ u16 sP[128 * 128];    // 32 KB, wave-local rows
  // XCD-chunked swizzle: 512 blocks, 8 XCDs, 64 logical per XCD (bijective).
  int wg = blockIdx.x;
  int logical = (wg & 7) * 64 + (wg >> 3);
  int ft = logical & 7, h = (logical >> 3) & 15, b = logical >> 7;
  int f0 = ft * 128;
  int bh = b * NUM_HEADS + h;
  const u16* Qg = Qh + ((size_t)bh * SEQ + f0) * 64;
  const u16* Kg = Kh + (size_t)bh * SEQ * 64;
  const u16* Vg = Vt + (size_t)bh * 64 * SEQ;
  int tid = threadIdx.x, w = tid >> 6, lane = tid & 63;
  int g = lane >> 4, cc = lane & 15;
  const int fbase = w * 32;

  // hoist flags (avoid mid-loop loads that disturb vmcnt counting)
  int flgmask = 0;
#pragma unroll
  for (int tt = 0; tt < 8; ++tt)
    flgmask |= (flags[(b * 8 + ft) * 8 + tt] != 0) << tt;

  int sx[4];
  const u16* kbase[4];
  const u16* vbase[4];
#pragma unroll
  for (int i = 0; i < 4; ++i) {
    int ch = w * 4 + i;
    int x = ch * 1024 + lane * 16;
    sx[i] = ch * 512;
    int r7 = x >> 7;
    int c7 = (x & 127) ^ ((r7 & 7) << 4);
    kbase[i] = Kg + (size_t)r7 * 64 + (c7 >> 1);
    int r8 = x >> 8;
    int c8 = (x & 255) ^ ((r8 & 7) << 4);
    vbase[i] = Vg + (size_t)r8 * SEQ + (c8 >> 1);
  }

  // Q fragments -> registers (one-time, L2-resident)
  bf16x8 aq[2][2];
#pragma unroll
  for (int kk = 0; kk < 2; ++kk)
#pragma unroll
    for (int mf = 0; mf < 2; ++mf)
      aq[kk][mf] = *(const bf16x8*)&Qg[(size_t)(fbase + mf * 16 + cc) * 64 + kk * 32 + g * 8];

  float m_run[8], l_run[8];
#pragma unroll
  for (int i = 0; i < 8; ++i) { m_run[i] = -3.0e38f; l_run[i] = 0.0f; }

  // prologue: stage K0 -> buf0
#pragma unroll
  for (int i = 0; i < 4; ++i) async16(&sK[0][sx[i]], kbase[i]);

  // ---- pass 1: online (m,l) in log2 domain ----
#pragma unroll 1
  for (int tt = 0; tt < 8; ++tt) {
    int cur = tt & 1;
    VMCNT0;
    BAR;
    SCHED0;
    if (tt < 7) {
#pragma unroll
      for (int i = 0; i < 4; ++i)
        async16(&sK[cur ^ 1][sx[i]], kbase[i] + (tt + 1) * 8192);
    }
    f32x4 s[2][8] = {};
#pragma unroll
    for (int kk = 0; kk < 2; ++kk) {
      bf16x8 bk8[8];
#pragma unroll
      for (int nf = 0; nf < 8; ++nf) {
        int row = nf * 16 + cc;
        int colb = (kk * 64 + (g << 4)) ^ ((row & 7) << 4);
        bk8[nf] = *(const bf16x8*)&sK[cur][(row * 128 + colb) >> 1];
      }
#pragma unroll
      for (int mf = 0; mf < 2; ++mf)
#pragma unroll
        for (int nf = 0; nf < 8; ++nf)
          s[mf][nf] = __builtin_amdgcn_mfma_f32_16x16x32_bf16(aq[kk][mf], bk8[nf], s[mf][nf], 0, 0, 0);
    }
#pragma unroll
    for (int mf = 0; mf < 2; ++mf)
#pragma unroll
      for (int nf = 0; nf < 8; ++nf)
        s[mf][nf] = s[mf][nf] * C1;
    if ((flgmask >> tt) & 1) {
      for (int mf = 0; mf < 2; ++mf)
        for (int nf = 0; nf < 8; ++nf)
          for (int r = 0; r < 4; ++r) {
            int frow = f0 + fbase + mf * 16 + g * 4 + r;
            int tcol = tt * 128 + nf * 16 + cc;
            s[mf][nf][r] += bf2f(adder[((size_t)b * SEQ + frow) * SEQ + tcol]);
          }
    }
#pragma unroll
    for (int mf = 0; mf < 2; ++mf)
#pragma unroll
      for (int r = 0; r < 4; ++r) {
        float tmax = s[mf][0][r];
#pragma unroll
        for (int nf = 1; nf < 8; ++nf) tmax = fmaxf(tmax, s[mf][nf][r]);
        tmax = fmaxf(tmax, __shfl_xor(tmax, 1, 16));
        tmax = fmaxf(tmax, __shfl_xor(tmax, 2, 16));
        tmax = fmaxf(tmax, __shfl_xor(tmax, 4, 16));
        tmax = fmaxf(tmax, __shfl_xor(tmax, 8, 16));
        int idx = mf * 4 + r;
        float mnew = fmaxf(m_run[idx], tmax);
        float sum = 0.f;
#pragma unroll
        for (int nf = 0; nf < 8; ++nf) sum += exp2f(s[mf][nf][r] - mnew);
        sum += __shfl_xor(sum, 1, 16);
        sum += __shfl_xor(sum, 2, 16);
        sum += __shfl_xor(sum, 4, 16);
        sum += __shfl_xor(sum, 8, 16);
        l_run[idx] = l_run[idx] * exp2f(m_run[idx] - mnew) + sum;
        m_run[idx] = mnew;
      }
  }

  float inv_l[8];
#pragma unroll
  for (int i = 0; i < 8; ++i) inv_l[i] = 1.0f / l_run[i];

  f32x4 accO[2][4] = {};

  // re-prime K0 for pass 2 (sK[0] readers finished >=2 barriers ago)
#pragma unroll
  for (int i = 0; i < 4; ++i) async16(&sK[0][sx[i]], kbase[i]);

  // ---- pass 2 ----
#pragma unroll 1
  for (int tt = 0; tt < 8; ++tt) {
    int cur = tt & 1;
    VMCNT0;  // K(tt) landed; prev tile's stores drained (had PV window)
    BAR;     // all waves done with prev sV
    SCHED0;
    // stage V(tt): hides under QK^T + softmax
#pragma unroll
    for (int i = 0; i < 4; ++i) async16(&sV[sx[i]], vbase[i] + tt * 128);

    f32x4 s[2][8] = {};
#pragma unroll
    for (int kk = 0; kk < 2; ++kk) {
      bf16x8 bk8[8];
#pragma unroll
      for (int nf = 0; nf < 8; ++nf) {
        int row = nf * 16 + cc;
        int colb = (kk * 64 + (g << 4)) ^ ((row & 7) << 4);
        bk8[nf] = *(const bf16x8*)&sK[cur][(row * 128 + colb) >> 1];
      }
#pragma unroll
      for (int mf = 0; mf < 2; ++mf)
#pragma unroll
        for (int nf = 0; nf < 8; ++nf)
          s[mf][nf] = __builtin_amdgcn_mfma_f32_16x16x32_bf16(aq[kk][mf], bk8[nf], s[mf][nf], 0, 0, 0);
    }
    // prefetch K(tt+1) into the other buffer; stays in flight across VMCNT4
    if (tt < 7) {
#pragma unroll
      for (int i = 0; i < 4; ++i)
        async16(&sK[cur ^ 1][sx[i]], kbase[i] + (tt + 1) * 8192);
    }
#pragma unroll
    for (int mf = 0; mf < 2; ++mf)
#pragma unroll
      for (int nf = 0; nf < 8; ++nf)
        s[mf][nf] = s[mf][nf] * C1;
    if ((flgmask >> tt) & 1) {
      for (int mf = 0; mf < 2; ++mf)
        for (int nf = 0; nf < 8; ++nf)
          for (int r = 0; r < 4; ++r) {
            int frow = f0 + fbase + mf * 16 + g * 4 + r;
            int tcol = tt * 128 + nf * 16 + cc;
            s[mf][nf][r] += bf2f(adder[((size_t)b * SEQ + frow) * SEQ + tcol]);
          }
    }
    // p = 2^(s2-m) * inv_l ; write bf16 to wave-local sP rows
#pragma unroll
    for (int mf = 0; mf < 2; ++mf)
#pragma unroll
      for (int nf = 0; nf < 8; ++nf)
#pragma unroll
        for (int r = 0; r < 4; ++r) {
          int idx = mf * 4 + r;
          float p = exp2f(s[mf][nf][r] - m_run[idx]) * inv_l[idx];
          int frow = fbase + mf * 16 + g * 4 + r;
          int tcol = nf * 16 + cc;
          sP[(frow * 256 + ((tcol * 2) ^ ((frow & 7) << 4))) >> 1] = f2bf(p);
        }
    // outstanding vmem: 4 V loads (oldest) + 4 K loads — NO stores.
    if (tt < 7) {
      VMCNT4;  // V landed; K(tt+1) stays in flight
    } else {
      VMCNT0;
    }
    BAR;  // sV visible to all waves
    SCHED0;
    // coalesced probs store (own rows from sP): drains under PV + next QK^T
#pragma unroll
    for (int sw = 0; sw < 8; ++sw) {
      int row = fbase + sw * 4 + (lane >> 4);
      int colb = ((lane & 15) * 16) ^ ((row & 7) << 4);
      u16x8 pv = *(const u16x8*)&sP[(row * 256 + colb) >> 1];
      float* dst = &probs[((size_t)bh * SEQ + f0 + row) * SEQ + tt * 128 + (lane & 15) * 8];
      f32x4 o0 = {bf2f(pv[0]), bf2f(pv[1]), bf2f(pv[2]), bf2f(pv[3])};
      f32x4 o1 = {bf2f(pv[4]), bf2f(pv[5]), bf2f(pv[6]), bf2f(pv[7])};
      *(f32x4*)dst = o0;
      *(f32x4*)(dst + 4) = o1;
    }
#pragma unroll
    for (int ks = 0; ks < 4; ++ks) {
      bf16x8 ap[2], bv8[4];
#pragma unroll
      for (int mf = 0; mf < 2; ++mf) {
        int row = fbase + mf * 16 + cc;
        int colb = (ks * 64 + (g << 4)) ^ ((row & 7) << 4);
        ap[mf] = *(const bf16x8*)&sP[(row * 256 + colb) >> 1];
      }
#pragma unroll
      for (int nf = 0; nf < 4; ++nf) {
        int row = nf * 16 + cc;
        int colb = (ks * 64 + (g << 4)) ^ ((row & 7) << 4);
        bv8[nf] = *(const bf16x8*)&sV[(row * 256 + colb) >> 1];
      }
#pragma unroll
      for (int mf = 0; mf < 2; ++mf)
#pragma unroll
        for (int nf = 0; nf < 4; ++nf)
          accO[mf][nf] = __builtin_amdgcn_mfma_f32_16x16x32_bf16(ap[mf], bv8[nf], accO[mf][nf], 0, 0, 0);
    }
  }

#pragma unroll
  for (int mf = 0; mf < 2; ++mf)
#pragma unroll
    for (int nf = 0; nf < 4; ++nf)
#pragma unroll
      for (int r = 0; r < 4; ++r) {
        int frow = fbase + mf * 16 + g * 4 + r;
        int d = nf * 16 + cc;
        ctx[((size_t)b * SEQ + f0 + frow) * HIDDEN + h * 64 + d] = accO[mf][nf][r];
      }
}

extern "C" void kernel_launch(void* const* d_in, const int* in_sizes, int n_in,
                              void* d_out, int out_size, void* d_ws, size_t ws_size,
                              hipStream_t stream) {
  const float* from = (const float*)d_in[0];
  const float* to   = (const float*)d_in[1];
  const float* mask = (const float*)d_in[2];
  const float* Wq   = (const float*)d_in[3];
  const float* bq   = (const float*)d_in[4];
  const float* Wk   = (const float*)d_in[5];
  const float* bk   = (const float*)d_in[6];
  const float* Wv   = (const float*)d_in[7];
  const float* bv   = (const float*)d_in[8];

  char* ws = (char*)d_ws;
  u16* Af    = (u16*)(ws);
  u16* At    = (u16*)(ws + 8388608);
  u16* Wt    = (u16*)(ws + 16777216);
  u16* adder = (u16*)(ws + 23068672);
  int* flags = (int*)(ws + 31457280);
  u16* Qh    = (u16*)(ws + 31458304);
  u16* Kh    = (u16*)(ws + 39846912);
  u16* Vt    = (u16*)(ws + 48235520);

  float* ctx = (float*)d_out;
  float* probs = ctx + (size_t)BATCH * SEQ * HIDDEN;

  k_cvt<<<dim3(2048, 1, 2), 256, 0, stream>>>(from, Af, to, At, 524288);
  k_wtrans<<<dim3(16, 16, 3), 256, 0, stream>>>(Wq, Wk, Wv, Wt);
  k_mask<<<dim3(8, 8, 4), 256, 0, stream>>>(mask, adder, flags);
  k_gemm<<<dim3(8, 32, 3), 256, 0, stream>>>(Af, At, Wt, bq, bk, bv, Qh, Kh, Vt);
  k_attn<<<512, 256, 0, stream>>>(Qh, Kh, Vt, adder, flags, ctx, probs);
}

// Round 5
// 225.525 us; speedup vs baseline: 1.0394x; 1.0163x over previous
//
#include <hip/hip_runtime.h>

typedef unsigned short u16;
typedef __bf16 bf16x8 __attribute__((ext_vector_type(8)));
typedef float f32x4 __attribute__((ext_vector_type(4)));
typedef u16 u16x8 __attribute__((ext_vector_type(8)));
typedef u16 u16x4 __attribute__((ext_vector_type(4)));

#define NUM_HEADS 16
#define HIDDEN 1024
#define BATCH 4
#define SEQ 1024
// 0.125 * log2(e): fold the 1/sqrt(64) scale and the exp->exp2 conversion
#define C1 0.1803368809109783f
#define LOG2E 1.4426950408889634f

#define VMCNT0 asm volatile("s_waitcnt vmcnt(0)" ::: "memory")
#define VMCNT4 asm volatile("s_waitcnt vmcnt(4)" ::: "memory")
#define VMCNT16 asm volatile("s_waitcnt vmcnt(16)" ::: "memory")
#define BAR __builtin_amdgcn_s_barrier()
#define SCHED0 __builtin_amdgcn_sched_barrier(0)

static __device__ __forceinline__ u16 f2bf(float x) {
  unsigned u = __float_as_uint(x);
  u = u + 0x7FFFu + ((u >> 16) & 1u);
  return (u16)(u >> 16);
}
static __device__ __forceinline__ float bf2f(u16 b) {
  return __uint_as_float(((unsigned)b) << 16);
}
static __device__ __forceinline__ void async16(u16* lds, const u16* g) {
  __builtin_amdgcn_global_load_lds(
      (const __attribute__((address_space(1))) void*)g,
      (__attribute__((address_space(3))) void*)lds, 16, 0, 0);
}

// ---------------- prep: fp32 -> bf16 (x8 per thread), z selects tensor ----------------
__global__ void k_cvt(const float* __restrict__ in0, u16* __restrict__ out0,
                      const float* __restrict__ in1, u16* __restrict__ out1, int n8) {
  int i = blockIdx.x * 256 + threadIdx.x;
  if (i >= n8) return;
  const float* in = blockIdx.z ? in1 : in0;
  u16* out = blockIdx.z ? out1 : out0;
  float4 a = ((const float4*)in)[i * 2];
  float4 b = ((const float4*)in)[i * 2 + 1];
  u16x8 v;
  v[0] = f2bf(a.x); v[1] = f2bf(a.y); v[2] = f2bf(a.z); v[3] = f2bf(a.w);
  v[4] = f2bf(b.x); v[5] = f2bf(b.y); v[6] = f2bf(b.z); v[7] = f2bf(b.w);
  *(u16x8*)&out[(size_t)i * 8] = v;
}

// ---------------- prep: W [K][N] fp32 -> Wt [N][K] bf16 ----------------
__global__ void k_wtrans(const float* __restrict__ Wq, const float* __restrict__ Wk,
                         const float* __restrict__ Wv, u16* __restrict__ Wt) {
  __shared__ float tile[64][65];
  const float* W = (blockIdx.z == 0) ? Wq : (blockIdx.z == 1) ? Wk : Wv;
  u16* out = Wt + (size_t)blockIdx.z * HIDDEN * HIDDEN;
  int k0 = blockIdx.y * 64, n0 = blockIdx.x * 64;
  int tid = threadIdx.x;
  int r = tid >> 6, c = tid & 63;
#pragma unroll
  for (int i = 0; i < 16; ++i)
    tile[i * 4 + r][c] = W[(size_t)(k0 + i * 4 + r) * HIDDEN + n0 + c];
  __syncthreads();
#pragma unroll
  for (int i = 0; i < 16; ++i)
    out[(size_t)(n0 + i * 4 + r) * HIDDEN + k0 + c] = f2bf(tile[c][i * 4 + r]);
}

// ---------------- prep: mask -> log2-domain bf16 adder + tile flags ----------------
__global__ void k_mask(const float* __restrict__ mask, u16* __restrict__ adder,
                       int* __restrict__ flags) {
  int tt = blockIdx.x, ft = blockIdx.y, b = blockIdx.z;
  int tid = threadIdx.x;
  __shared__ int sflag;
  if (tid == 0) sflag = 0;
  __syncthreads();
  size_t base = ((size_t)b * SEQ + ft * 128) * SEQ + tt * 128;
  int any = 0;
#pragma unroll
  for (int i = 0; i < 16; ++i) {
    int idx = i * 256 + tid;
    int r = idx >> 5, c4 = idx & 31;
    float4 v = *(const float4*)&mask[base + (size_t)r * SEQ + c4 * 4];
    any |= (v.x != 1.0f) | (v.y != 1.0f) | (v.z != 1.0f) | (v.w != 1.0f);
  }
  if (any) sflag = 1;
  __syncthreads();
  if (sflag) {
#pragma unroll
    for (int i = 0; i < 16; ++i) {
      int idx = i * 256 + tid;
      int r = idx >> 5, c4 = idx & 31;
      float4 v = *(const float4*)&mask[base + (size_t)r * SEQ + c4 * 4];
      u16x4 o;
      o[0] = f2bf((1.0f - v.x) * -10000.0f * LOG2E);
      o[1] = f2bf((1.0f - v.y) * -10000.0f * LOG2E);
      o[2] = f2bf((1.0f - v.z) * -10000.0f * LOG2E);
      o[3] = f2bf((1.0f - v.w) * -10000.0f * LOG2E);
      *(u16x4*)&adder[base + (size_t)r * SEQ + c4 * 4] = o;
    }
  }
  if (tid == 0) flags[(b * 8 + ft) * 8 + tt] = sflag;
}

// ---------------- QKV GEMM: 128x128 tile, BK=64, single-buffer ----------------
// V epilogue: LDS-transposed coalesced stores (Vt layout [d][s] needs transpose).
__global__ __launch_bounds__(256) void k_gemm(
    const u16* __restrict__ Af, const u16* __restrict__ At,
    const u16* __restrict__ Wt,
    const float* __restrict__ bq, const float* __restrict__ bk, const float* __restrict__ bv,
    u16* __restrict__ Qh, u16* __restrict__ Kh, u16* __restrict__ Vt) {
  __shared__ u16 sAB[2 * 128 * 64];  // sA | sB ; reused as 128x128 transpose tile
  u16* sA = sAB;
  u16* sB = sAB + 128 * 64;
  int which = blockIdx.z;
  const u16* A = (which == 0) ? Af : At;
  const u16* B = Wt + (size_t)which * HIDDEN * HIDDEN;
  const float* bias = (which == 0) ? bq : (which == 1) ? bk : bv;
  int m0 = blockIdx.y * 128, n0 = blockIdx.x * 128;
  int tid = threadIdx.x, w = tid >> 6, lane = tid & 63;
  int wr = w >> 1, wc = w & 1;
  int g = lane >> 4, cc = lane & 15;

  f32x4 acc[4][4] = {};

  int sx[4], srow[4], scol[4];
#pragma unroll
  for (int i = 0; i < 4; ++i) {
    int ch = w * 4 + i;
    int x = ch * 1024 + lane * 16;
    int row = x >> 7;
    int colb = (x & 127) ^ ((row & 7) << 4);  // pre-swizzled source
    sx[i] = ch * 512;
    srow[i] = row;
    scol[i] = colb >> 1;
  }

  for (int kt = 0; kt < HIDDEN / 64; ++kt) {
    __syncthreads();
#pragma unroll
    for (int i = 0; i < 4; ++i) {
      async16(&sA[sx[i]], A + (size_t)(m0 + srow[i]) * HIDDEN + kt * 64 + scol[i]);
      async16(&sB[sx[i]], B + (size_t)(n0 + srow[i]) * HIDDEN + kt * 64 + scol[i]);
    }
    asm volatile("s_waitcnt vmcnt(0)" ::: "memory");
    __syncthreads();
#pragma unroll
    for (int kk = 0; kk < 2; ++kk) {
      bf16x8 af[4], bfr[4];
#pragma unroll
      for (int mf = 0; mf < 4; ++mf) {
        int row = wr * 64 + mf * 16 + cc;
        int colb = (kk * 64 + (g << 4)) ^ ((row & 7) << 4);
        af[mf] = *(const bf16x8*)&sA[(row * 128 + colb) >> 1];
      }
#pragma unroll
      for (int nf = 0; nf < 4; ++nf) {
        int row = wc * 64 + nf * 16 + cc;
        int colb = (kk * 64 + (g << 4)) ^ ((row & 7) << 4);
        bfr[nf] = *(const bf16x8*)&sB[(row * 128 + colb) >> 1];
      }
#pragma unroll
      for (int mf = 0; mf < 4; ++mf)
#pragma unroll
        for (int nf = 0; nf < 4; ++nf)
          acc[mf][nf] = __builtin_amdgcn_mfma_f32_16x16x32_bf16(af[mf], bfr[nf], acc[mf][nf], 0, 0, 0);
    }
  }

  if (which != 2) {
#pragma unroll
    for (int mf = 0; mf < 4; ++mf) {
#pragma unroll
      for (int nf = 0; nf < 4; ++nf) {
        int n = n0 + wc * 64 + nf * 16 + cc;
        float bval = bias[n];
        int h = n >> 6, d = n & 63;
#pragma unroll
        for (int r = 0; r < 4; ++r) {
          int m = m0 + wr * 64 + mf * 16 + g * 4 + r;
          int b = m >> 10, s = m & 1023;
          u16 o = f2bf(acc[mf][nf][r] + bval);
          if (which == 0)
            Qh[((((size_t)b * NUM_HEADS + h) * SEQ + s) << 6) + d] = o;
          else
            Kh[((((size_t)b * NUM_HEADS + h) * SEQ + s) << 6) + d] = o;
        }
      }
    }
  } else {
    // V: transpose via LDS, then coalesced stores along s.
    __syncthreads();  // done with sA/sB MFMA reads
    char* T = (char*)sAB;  // [n_local 128][m_local 128] bf16, XOR-swizzled
#pragma unroll
    for (int mf = 0; mf < 4; ++mf) {
#pragma unroll
      for (int nf = 0; nf < 4; ++nf) {
        int nl = wc * 64 + nf * 16 + cc;
        float bval = bias[n0 + nl];
        int mlb = wr * 64 + mf * 16 + g * 4;
        u16x4 v;
#pragma unroll
        for (int r = 0; r < 4; ++r) v[r] = f2bf(acc[mf][nf][r] + bval);
        int byte = nl * 256 + ((mlb * 2) ^ ((nl & 7) << 4));
        *(u16x4*)(T + byte) = v;
      }
    }
    __syncthreads();
    int nl = tid >> 1, mh = (tid & 1) * 64;
    int b = m0 >> 10, s0 = m0 & 1023;
    u16* dst = &Vt[((size_t)b * 1024 + n0 + nl) * SEQ + s0 + mh];
#pragma unroll
    for (int j = 0; j < 8; ++j) {
      int byte = nl * 256 + (((mh + j * 8) * 2) ^ ((nl & 7) << 4));
      *(u16x8*)&dst[j * 8] = *(const u16x8*)(T + byte);
    }
  }
}

// ---------------- fused attention: 2-pass online softmax ----------------
// Pass-2: counted waits never drain the probs-store stream.
// sP is wave-private (each wave reads only its own 32 rows) -> stores after PV.
__global__ __launch_bounds__(256) void k_attn(
    const u16* __restrict__ Qh, const u16* __restrict__ Kh, const u16* __restrict__ Vt,
    const u16* __restrict__ adder, const int* __restrict__ flags,
    float* __restrict__ ctx, float* __restrict__ probs) {
  __shared__ u16 sK[2][128 * 64];  // 32 KB, dbuf
  __shared__ u16 sV[64 * 128];     // 16 KB
  __shared__ u16 sP[128 * 128];    // 32 KB, wave-private rows
  // XCD-chunked swizzle: 512 blocks, 8 XCDs, 64 logical per XCD (bijective).
  int wg = blockIdx.x;
  int logical = (wg & 7) * 64 + (wg >> 3);
  int ft = logical & 7, h = (logical >> 3) & 15, b = logical >> 7;
  int f0 = ft * 128;
  int bh = b * NUM_HEADS + h;
  const u16* Qg = Qh + ((size_t)bh * SEQ + f0) * 64;
  const u16* Kg = Kh + (size_t)bh * SEQ * 64;
  const u16* Vg = Vt + (size_t)bh * 64 * SEQ;
  int tid = threadIdx.x, w = tid >> 6, lane = tid & 63;
  int g = lane >> 4, cc = lane & 15;
  const int fbase = w * 32;

  int flgmask = 0;
#pragma unroll
  for (int tt = 0; tt < 8; ++tt)
    flgmask |= (flags[(b * 8 + ft) * 8 + tt] != 0) << tt;

  int sx[4];
  const u16* kbase[4];
  const u16* vbase[4];
#pragma unroll
  for (int i = 0; i < 4; ++i) {
    int ch = w * 4 + i;
    int x = ch * 1024 + lane * 16;
    sx[i] = ch * 512;
    int r7 = x >> 7;
    int c7 = (x & 127) ^ ((r7 & 7) << 4);
    kbase[i] = Kg + (size_t)r7 * 64 + (c7 >> 1);
    int r8 = x >> 8;
    int c8 = (x & 255) ^ ((r8 & 7) << 4);
    vbase[i] = Vg + (size_t)r8 * SEQ + (c8 >> 1);
  }

  // Q fragments -> registers (one-time, L2-resident)
  bf16x8 aq[2][2];
#pragma unroll
  for (int kk = 0; kk < 2; ++kk)
#pragma unroll
    for (int mf = 0; mf < 2; ++mf)
      aq[kk][mf] = *(const bf16x8*)&Qg[(size_t)(fbase + mf * 16 + cc) * 64 + kk * 32 + g * 8];

  float m_run[8], l_run[8];
#pragma unroll
  for (int i = 0; i < 8; ++i) { m_run[i] = -3.0e38f; l_run[i] = 0.0f; }

  // prologue: stage K0 -> buf0
#pragma unroll
  for (int i = 0; i < 4; ++i) async16(&sK[0][sx[i]], kbase[i]);

  // ---- pass 1: online (m,l) in log2 domain ----
#pragma unroll 1
  for (int tt = 0; tt < 8; ++tt) {
    int cur = tt & 1;
    VMCNT0;
    BAR;
    SCHED0;
    if (tt < 7) {
#pragma unroll
      for (int i = 0; i < 4; ++i)
        async16(&sK[cur ^ 1][sx[i]], kbase[i] + (tt + 1) * 8192);
    }
    f32x4 s[2][8] = {};
#pragma unroll
    for (int kk = 0; kk < 2; ++kk) {
      bf16x8 bk8[8];
#pragma unroll
      for (int nf = 0; nf < 8; ++nf) {
        int row = nf * 16 + cc;
        int colb = (kk * 64 + (g << 4)) ^ ((row & 7) << 4);
        bk8[nf] = *(const bf16x8*)&sK[cur][(row * 128 + colb) >> 1];
      }
#pragma unroll
      for (int mf = 0; mf < 2; ++mf)
#pragma unroll
        for (int nf = 0; nf < 8; ++nf)
          s[mf][nf] = __builtin_amdgcn_mfma_f32_16x16x32_bf16(aq[kk][mf], bk8[nf], s[mf][nf], 0, 0, 0);
    }
#pragma unroll
    for (int mf = 0; mf < 2; ++mf)
#pragma unroll
      for (int nf = 0; nf < 8; ++nf)
        s[mf][nf] = s[mf][nf] * C1;
    if ((flgmask >> tt) & 1) {
      for (int mf = 0; mf < 2; ++mf)
        for (int nf = 0; nf < 8; ++nf)
          for (int r = 0; r < 4; ++r) {
            int frow = f0 + fbase + mf * 16 + g * 4 + r;
            int tcol = tt * 128 + nf * 16 + cc;
            s[mf][nf][r] += bf2f(adder[((size_t)b * SEQ + frow) * SEQ + tcol]);
          }
    }
#pragma unroll
    for (int mf = 0; mf < 2; ++mf)
#pragma unroll
      for (int r = 0; r < 4; ++r) {
        float tmax = s[mf][0][r];
#pragma unroll
        for (int nf = 1; nf < 8; ++nf) tmax = fmaxf(tmax, s[mf][nf][r]);
        tmax = fmaxf(tmax, __shfl_xor(tmax, 1, 16));
        tmax = fmaxf(tmax, __shfl_xor(tmax, 2, 16));
        tmax = fmaxf(tmax, __shfl_xor(tmax, 4, 16));
        tmax = fmaxf(tmax, __shfl_xor(tmax, 8, 16));
        int idx = mf * 4 + r;
        float mnew = fmaxf(m_run[idx], tmax);
        float sum = 0.f;
#pragma unroll
        for (int nf = 0; nf < 8; ++nf) sum += exp2f(s[mf][nf][r] - mnew);
        sum += __shfl_xor(sum, 1, 16);
        sum += __shfl_xor(sum, 2, 16);
        sum += __shfl_xor(sum, 4, 16);
        sum += __shfl_xor(sum, 8, 16);
        l_run[idx] = l_run[idx] * exp2f(m_run[idx] - mnew) + sum;
        m_run[idx] = mnew;
      }
  }

  float inv_l[8];
#pragma unroll
  for (int i = 0; i < 8; ++i) inv_l[i] = 1.0f / l_run[i];

  f32x4 accO[2][4] = {};

  // re-prime K0 for pass 2
#pragma unroll
  for (int i = 0; i < 4; ++i) async16(&sK[0][sx[i]], kbase[i]);

  // ---- pass 2 ----
#pragma unroll 1
  for (int tt = 0; tt < 8; ++tt) {
    int cur = tt & 1;
    // tt==0: only K0 in flight -> full drain. tt>0: [K(tt) x4 oldest, stores x16]
    // -> VMCNT16 drains exactly K(tt); stores keep draining under QK^T+softmax.
    if (tt == 0) { VMCNT0; } else { VMCNT16; }
    BAR;   // all waves done reading sV(tt-1)
    SCHED0;
    // stage V(tt): hides under QK^T + softmax
#pragma unroll
    for (int i = 0; i < 4; ++i) async16(&sV[sx[i]], vbase[i] + tt * 128);

    f32x4 s[2][8] = {};
#pragma unroll
    for (int kk = 0; kk < 2; ++kk) {
      bf16x8 bk8[8];
#pragma unroll
      for (int nf = 0; nf < 8; ++nf) {
        int row = nf * 16 + cc;
        int colb = (kk * 64 + (g << 4)) ^ ((row & 7) << 4);
        bk8[nf] = *(const bf16x8*)&sK[cur][(row * 128 + colb) >> 1];
      }
#pragma unroll
      for (int mf = 0; mf < 2; ++mf)
#pragma unroll
        for (int nf = 0; nf < 8; ++nf)
          s[mf][nf] = __builtin_amdgcn_mfma_f32_16x16x32_bf16(aq[kk][mf], bk8[nf], s[mf][nf], 0, 0, 0);
    }
    // prefetch K(tt+1); stays in flight across the counted wait below
    if (tt < 7) {
#pragma unroll
      for (int i = 0; i < 4; ++i)
        async16(&sK[cur ^ 1][sx[i]], kbase[i] + (tt + 1) * 8192);
    }
#pragma unroll
    for (int mf = 0; mf < 2; ++mf)
#pragma unroll
      for (int nf = 0; nf < 8; ++nf)
        s[mf][nf] = s[mf][nf] * C1;
    if ((flgmask >> tt) & 1) {
      for (int mf = 0; mf < 2; ++mf)
        for (int nf = 0; nf < 8; ++nf)
          for (int r = 0; r < 4; ++r) {
            int frow = f0 + fbase + mf * 16 + g * 4 + r;
            int tcol = tt * 128 + nf * 16 + cc;
            s[mf][nf][r] += bf2f(adder[((size_t)b * SEQ + frow) * SEQ + tcol]);
          }
    }
    // p -> wave-private sP rows (bf16)
#pragma unroll
    for (int mf = 0; mf < 2; ++mf)
#pragma unroll
      for (int nf = 0; nf < 8; ++nf)
#pragma unroll
        for (int r = 0; r < 4; ++r) {
          int idx = mf * 4 + r;
          float p = exp2f(s[mf][nf][r] - m_run[idx]) * inv_l[idx];
          int frow = fbase + mf * 16 + g * 4 + r;
          int tcol = nf * 16 + cc;
          sP[(frow * 256 + ((tcol * 2) ^ ((frow & 7) << 4))) >> 1] = f2bf(p);
        }
    // wait for V only: [stores(tt-1) x16?, V x4, K(tt+1) x4] -> <=4 leaves K.
    // (stores had the whole QK^T+softmax to drain). tt==7: no K in flight.
    if (tt < 7) {
      VMCNT4;
    } else {
      VMCNT0;
    }
    BAR;  // sV(tt) visible to all waves
    SCHED0;
#pragma unroll
    for (int ks = 0; ks < 4; ++ks) {
      bf16x8 ap[2], bv8[4];
#pragma unroll
      for (int mf = 0; mf < 2; ++mf) {
        int row = fbase + mf * 16 + cc;
        int colb = (ks * 64 + (g << 4)) ^ ((row & 7) << 4);
        ap[mf] = *(const bf16x8*)&sP[(row * 256 + colb) >> 1];
      }
#pragma unroll
      for (int nf = 0; nf < 4; ++nf) {
        int row = nf * 16 + cc;
        int colb = (ks * 64 + (g << 4)) ^ ((row & 7) << 4);
        bv8[nf] = *(const bf16x8*)&sV[(row * 256 + colb) >> 1];
      }
#pragma unroll
      for (int mf = 0; mf < 2; ++mf)
#pragma unroll
        for (int nf = 0; nf < 4; ++nf)
          accO[mf][nf] = __builtin_amdgcn_mfma_f32_16x16x32_bf16(ap[mf], bv8[nf], accO[mf][nf], 0, 0, 0);
    }
    // probs stores AFTER PV (sP rows are wave-private; no barrier needed).
    // These drain under next tile's QK^T+softmax.
#pragma unroll
    for (int sw = 0; sw < 8; ++sw) {
      int row = fbase + sw * 4 + (lane >> 4);
      int colb = ((lane & 15) * 16) ^ ((row & 7) << 4);
      u16x8 pv = *(const u16x8*)&sP[(row * 256 + colb) >> 1];
      float* dst = &probs[((size_t)bh * SEQ + f0 + row) * SEQ + tt * 128 + (lane & 15) * 8];
      f32x4 o0 = {bf2f(pv[0]), bf2f(pv[1]), bf2f(pv[2]), bf2f(pv[3])};
      f32x4 o1 = {bf2f(pv[4]), bf2f(pv[5]), bf2f(pv[6]), bf2f(pv[7])};
      *(f32x4*)dst = o0;
      *(f32x4*)(dst + 4) = o1;
    }
  }

#pragma unroll
  for (int mf = 0; mf < 2; ++mf)
#pragma unroll
    for (int nf = 0; nf < 4; ++nf)
#pragma unroll
      for (int r = 0; r < 4; ++r) {
        int frow = fbase + mf * 16 + g * 4 + r;
        int d = nf * 16 + cc;
        ctx[((size_t)b * SEQ + f0 + frow) * HIDDEN + h * 64 + d] = accO[mf][nf][r];
      }
}

extern "C" void kernel_launch(void* const* d_in, const int* in_sizes, int n_in,
                              void* d_out, int out_size, void* d_ws, size_t ws_size,
                              hipStream_t stream) {
  const float* from = (const float*)d_in[0];
  const float* to   = (const float*)d_in[1];
  const float* mask = (const float*)d_in[2];
  const float* Wq   = (const float*)d_in[3];
  const float* bq   = (const float*)d_in[4];
  const float* Wk   = (const float*)d_in[5];
  const float* bk   = (const float*)d_in[6];
  const float* Wv   = (const float*)d_in[7];
  const float* bv   = (const float*)d_in[8];

  char* ws = (char*)d_ws;
  u16* Af    = (u16*)(ws);
  u16* At    = (u16*)(ws + 8388608);
  u16* Wt    = (u16*)(ws + 16777216);
  u16* adder = (u16*)(ws + 23068672);
  int* flags = (int*)(ws + 31457280);
  u16* Qh    = (u16*)(ws + 31458304);
  u16* Kh    = (u16*)(ws + 39846912);
  u16* Vt    = (u16*)(ws + 48235520);

  float* ctx = (float*)d_out;
  float* probs = ctx + (size_t)BATCH * SEQ * HIDDEN;

  k_cvt<<<dim3(2048, 1, 2), 256, 0, stream>>>(from, Af, to, At, 524288);
  k_wtrans<<<dim3(16, 16, 3), 256, 0, stream>>>(Wq, Wk, Wv, Wt);
  k_mask<<<dim3(8, 8, 4), 256, 0, stream>>>(mask, adder, flags);
  k_gemm<<<dim3(8, 32, 3), 256, 0, stream>>>(Af, At, Wt, bq, bk, bv, Qh, Kh, Vt);
  k_attn<<<512, 256, 0, stream>>>(Qh, Kh, Vt, adder, flags, ctx, probs);
}

// Round 6
// 210.574 us; speedup vs baseline: 1.1132x; 1.0710x over previous
//
#include <hip/hip_runtime.h>

typedef unsigned short u16;
typedef __bf16 bf16x8 __attribute__((ext_vector_type(8)));
typedef float f32x4 __attribute__((ext_vector_type(4)));
typedef u16 u16x8 __attribute__((ext_vector_type(8)));
typedef u16 u16x4 __attribute__((ext_vector_type(4)));

#define NUM_HEADS 16
#define HIDDEN 1024
#define BATCH 4
#define SEQ 1024
// 0.125 * log2(e): fold the 1/sqrt(64) scale and the exp->exp2 conversion
#define C1 0.1803368809109783f
#define LOG2E 1.4426950408889634f

#define VMCNT0 asm volatile("s_waitcnt vmcnt(0)" ::: "memory")

static __device__ __forceinline__ u16 f2bf(float x) {
  unsigned u = __float_as_uint(x);
  u = u + 0x7FFFu + ((u >> 16) & 1u);
  return (u16)(u >> 16);
}
static __device__ __forceinline__ float bf2f(u16 b) {
  return __uint_as_float(((unsigned)b) << 16);
}
static __device__ __forceinline__ void async16(u16* lds, const u16* g) {
  __builtin_amdgcn_global_load_lds(
      (const __attribute__((address_space(1))) void*)g,
      (__attribute__((address_space(3))) void*)lds, 16, 0, 0);
}

// ---------------- prep: fp32 -> bf16 (x8 per thread), z selects tensor ----------------
__global__ void k_cvt(const float* __restrict__ in0, u16* __restrict__ out0,
                      const float* __restrict__ in1, u16* __restrict__ out1, int n8) {
  int i = blockIdx.x * 256 + threadIdx.x;
  if (i >= n8) return;
  const float* in = blockIdx.z ? in1 : in0;
  u16* out = blockIdx.z ? out1 : out0;
  float4 a = ((const float4*)in)[i * 2];
  float4 b = ((const float4*)in)[i * 2 + 1];
  u16x8 v;
  v[0] = f2bf(a.x); v[1] = f2bf(a.y); v[2] = f2bf(a.z); v[3] = f2bf(a.w);
  v[4] = f2bf(b.x); v[5] = f2bf(b.y); v[6] = f2bf(b.z); v[7] = f2bf(b.w);
  *(u16x8*)&out[(size_t)i * 8] = v;
}

// ---------------- prep: W [K][N] fp32 -> Wt [N][K] bf16 ----------------
__global__ void k_wtrans(const float* __restrict__ Wq, const float* __restrict__ Wk,
                         const float* __restrict__ Wv, u16* __restrict__ Wt) {
  __shared__ float tile[64][65];
  const float* W = (blockIdx.z == 0) ? Wq : (blockIdx.z == 1) ? Wk : Wv;
  u16* out = Wt + (size_t)blockIdx.z * HIDDEN * HIDDEN;
  int k0 = blockIdx.y * 64, n0 = blockIdx.x * 64;
  int tid = threadIdx.x;
  int r = tid >> 6, c = tid & 63;
#pragma unroll
  for (int i = 0; i < 16; ++i)
    tile[i * 4 + r][c] = W[(size_t)(k0 + i * 4 + r) * HIDDEN + n0 + c];
  __syncthreads();
#pragma unroll
  for (int i = 0; i < 16; ++i)
    out[(size_t)(n0 + i * 4 + r) * HIDDEN + k0 + c] = f2bf(tile[c][i * 4 + r]);
}

// ---------------- prep: mask -> log2-domain bf16 adder + tile flags ----------------
__global__ void k_mask(const float* __restrict__ mask, u16* __restrict__ adder,
                       int* __restrict__ flags) {
  int tt = blockIdx.x, ft = blockIdx.y, b = blockIdx.z;
  int tid = threadIdx.x;
  __shared__ int sflag;
  if (tid == 0) sflag = 0;
  __syncthreads();
  size_t base = ((size_t)b * SEQ + ft * 128) * SEQ + tt * 128;
  int any = 0;
#pragma unroll
  for (int i = 0; i < 16; ++i) {
    int idx = i * 256 + tid;
    int r = idx >> 5, c4 = idx & 31;
    float4 v = *(const float4*)&mask[base + (size_t)r * SEQ + c4 * 4];
    any |= (v.x != 1.0f) | (v.y != 1.0f) | (v.z != 1.0f) | (v.w != 1.0f);
  }
  if (any) sflag = 1;
  __syncthreads();
  if (sflag) {
#pragma unroll
    for (int i = 0; i < 16; ++i) {
      int idx = i * 256 + tid;
      int r = idx >> 5, c4 = idx & 31;
      float4 v = *(const float4*)&mask[base + (size_t)r * SEQ + c4 * 4];
      u16x4 o;
      o[0] = f2bf((1.0f - v.x) * -10000.0f * LOG2E);
      o[1] = f2bf((1.0f - v.y) * -10000.0f * LOG2E);
      o[2] = f2bf((1.0f - v.z) * -10000.0f * LOG2E);
      o[3] = f2bf((1.0f - v.w) * -10000.0f * LOG2E);
      *(u16x4*)&adder[base + (size_t)r * SEQ + c4 * 4] = o;
    }
  }
  if (tid == 0) flags[(b * 8 + ft) * 8 + tt] = sflag;
}

// ---------------- QKV GEMM: 128x128 tile, BK=64, single-buffer ----------------
// V epilogue: LDS-transposed coalesced stores (Vt layout [d][s] needs transpose).
__global__ __launch_bounds__(256) void k_gemm(
    const u16* __restrict__ Af, const u16* __restrict__ At,
    const u16* __restrict__ Wt,
    const float* __restrict__ bq, const float* __restrict__ bk, const float* __restrict__ bv,
    u16* __restrict__ Qh, u16* __restrict__ Kh, u16* __restrict__ Vt) {
  __shared__ u16 sAB[2 * 128 * 64];  // sA | sB ; reused as 128x128 transpose tile
  u16* sA = sAB;
  u16* sB = sAB + 128 * 64;
  int which = blockIdx.z;
  const u16* A = (which == 0) ? Af : At;
  const u16* B = Wt + (size_t)which * HIDDEN * HIDDEN;
  const float* bias = (which == 0) ? bq : (which == 1) ? bk : bv;
  int m0 = blockIdx.y * 128, n0 = blockIdx.x * 128;
  int tid = threadIdx.x, w = tid >> 6, lane = tid & 63;
  int wr = w >> 1, wc = w & 1;
  int g = lane >> 4, cc = lane & 15;

  f32x4 acc[4][4] = {};

  int sx[4], srow[4], scol[4];
#pragma unroll
  for (int i = 0; i < 4; ++i) {
    int ch = w * 4 + i;
    int x = ch * 1024 + lane * 16;
    int row = x >> 7;
    int colb = (x & 127) ^ ((row & 7) << 4);  // pre-swizzled source
    sx[i] = ch * 512;
    srow[i] = row;
    scol[i] = colb >> 1;
  }

  for (int kt = 0; kt < HIDDEN / 64; ++kt) {
    __syncthreads();
#pragma unroll
    for (int i = 0; i < 4; ++i) {
      async16(&sA[sx[i]], A + (size_t)(m0 + srow[i]) * HIDDEN + kt * 64 + scol[i]);
      async16(&sB[sx[i]], B + (size_t)(n0 + srow[i]) * HIDDEN + kt * 64 + scol[i]);
    }
    VMCNT0;
    __syncthreads();
#pragma unroll
    for (int kk = 0; kk < 2; ++kk) {
      bf16x8 af[4], bfr[4];
#pragma unroll
      for (int mf = 0; mf < 4; ++mf) {
        int row = wr * 64 + mf * 16 + cc;
        int colb = (kk * 64 + (g << 4)) ^ ((row & 7) << 4);
        af[mf] = *(const bf16x8*)&sA[(row * 128 + colb) >> 1];
      }
#pragma unroll
      for (int nf = 0; nf < 4; ++nf) {
        int row = wc * 64 + nf * 16 + cc;
        int colb = (kk * 64 + (g << 4)) ^ ((row & 7) << 4);
        bfr[nf] = *(const bf16x8*)&sB[(row * 128 + colb) >> 1];
      }
#pragma unroll
      for (int mf = 0; mf < 4; ++mf)
#pragma unroll
        for (int nf = 0; nf < 4; ++nf)
          acc[mf][nf] = __builtin_amdgcn_mfma_f32_16x16x32_bf16(af[mf], bfr[nf], acc[mf][nf], 0, 0, 0);
    }
  }

  if (which != 2) {
#pragma unroll
    for (int mf = 0; mf < 4; ++mf) {
#pragma unroll
      for (int nf = 0; nf < 4; ++nf) {
        int n = n0 + wc * 64 + nf * 16 + cc;
        float bval = bias[n];
        int h = n >> 6, d = n & 63;
#pragma unroll
        for (int r = 0; r < 4; ++r) {
          int m = m0 + wr * 64 + mf * 16 + g * 4 + r;
          int b = m >> 10, s = m & 1023;
          u16 o = f2bf(acc[mf][nf][r] + bval);
          if (which == 0)
            Qh[((((size_t)b * NUM_HEADS + h) * SEQ + s) << 6) + d] = o;
          else
            Kh[((((size_t)b * NUM_HEADS + h) * SEQ + s) << 6) + d] = o;
        }
      }
    }
  } else {
    // V: transpose via LDS, then coalesced stores along s.
    __syncthreads();  // done with sA/sB MFMA reads
    char* T = (char*)sAB;  // [n_local 128][m_local 128] bf16, XOR-swizzled
#pragma unroll
    for (int mf = 0; mf < 4; ++mf) {
#pragma unroll
      for (int nf = 0; nf < 4; ++nf) {
        int nl = wc * 64 + nf * 16 + cc;
        float bval = bias[n0 + nl];
        int mlb = wr * 64 + mf * 16 + g * 4;
        u16x4 v;
#pragma unroll
        for (int r = 0; r < 4; ++r) v[r] = f2bf(acc[mf][nf][r] + bval);
        int byte = nl * 256 + ((mlb * 2) ^ ((nl & 7) << 4));
        *(u16x4*)(T + byte) = v;
      }
    }
    __syncthreads();
    int nl = tid >> 1, mh = (tid & 1) * 64;
    int b = m0 >> 10, s0 = m0 & 1023;
    u16* dst = &Vt[((size_t)b * 1024 + n0 + nl) * SEQ + s0 + mh];
#pragma unroll
    for (int j = 0; j < 8; ++j) {
      int byte = nl * 256 + (((mh + j * 8) * 2) ^ ((nl & 7) << 4));
      *(u16x8*)&dst[j * 8] = *(const u16x8*)(T + byte);
    }
  }
}

// ---------------- fused attention: R1 structure (2-pass online softmax) ----------------
__global__ __launch_bounds__(256) void k_attn(
    const u16* __restrict__ Qh, const u16* __restrict__ Kh, const u16* __restrict__ Vt,
    const u16* __restrict__ adder, const int* __restrict__ flags,
    float* __restrict__ ctx, float* __restrict__ probs) {
  __shared__ u16 sQ[128 * 64];   // 16 KB, rows 128 B, swizzled
  __shared__ u16 sK[128 * 64];   // 16 KB
  __shared__ u16 sV[64 * 128];   // 16 KB, rows 256 B (V^T slice), swizzled
  __shared__ u16 sP[128 * 128];  // 32 KB, rows 256 B, swizzled
  int ft = blockIdx.x, h = blockIdx.y, b = blockIdx.z;
  int f0 = ft * 128;
  int bh = b * NUM_HEADS + h;
  const u16* Qg = Qh + ((size_t)bh * SEQ + f0) * 64;
  const u16* Kg = Kh + (size_t)bh * SEQ * 64;
  const u16* Vg = Vt + (size_t)bh * 64 * SEQ;
  int tid = threadIdx.x, w = tid >> 6, lane = tid & 63;
  int g = lane >> 4, cc = lane & 15;
  const int fbase = w * 32;

  int sx[4], srow7[4], scol7[4], srow8[4], scol8[4];
#pragma unroll
  for (int i = 0; i < 4; ++i) {
    int ch = w * 4 + i;
    int x = ch * 1024 + lane * 16;
    sx[i] = ch * 512;
    int r7 = x >> 7;
    int c7 = (x & 127) ^ ((r7 & 7) << 4);
    srow7[i] = r7; scol7[i] = c7 >> 1;
    int r8 = x >> 8;
    int c8 = (x & 255) ^ ((r8 & 7) << 4);
    srow8[i] = r8; scol8[i] = c8 >> 1;
  }

#pragma unroll
  for (int i = 0; i < 4; ++i)
    async16(&sQ[sx[i]], Qg + (size_t)srow7[i] * 64 + scol7[i]);

  float m_run[8], l_run[8];
#pragma unroll
  for (int i = 0; i < 8; ++i) { m_run[i] = -3.0e38f; l_run[i] = 0.0f; }

  // ---- pass 1: online (m,l) in log2 domain ----
  for (int tt = 0; tt < 8; ++tt) {
    __syncthreads();
#pragma unroll
    for (int i = 0; i < 4; ++i)
      async16(&sK[sx[i]], Kg + (size_t)(tt * 128 + srow7[i]) * 64 + scol7[i]);
    VMCNT0;
    __syncthreads();

    f32x4 s[2][8] = {};
#pragma unroll
    for (int kk = 0; kk < 2; ++kk) {
      bf16x8 aq[2], bk8[8];
#pragma unroll
      for (int mf = 0; mf < 2; ++mf) {
        int row = fbase + mf * 16 + cc;
        int colb = (kk * 64 + (g << 4)) ^ ((row & 7) << 4);
        aq[mf] = *(const bf16x8*)&sQ[(row * 128 + colb) >> 1];
      }
#pragma unroll
      for (int nf = 0; nf < 8; ++nf) {
        int row = nf * 16 + cc;
        int colb = (kk * 64 + (g << 4)) ^ ((row & 7) << 4);
        bk8[nf] = *(const bf16x8*)&sK[(row * 128 + colb) >> 1];
      }
#pragma unroll
      for (int mf = 0; mf < 2; ++mf)
#pragma unroll
        for (int nf = 0; nf < 8; ++nf)
          s[mf][nf] = __builtin_amdgcn_mfma_f32_16x16x32_bf16(aq[mf], bk8[nf], s[mf][nf], 0, 0, 0);
    }
    int flg = flags[(b * 8 + ft) * 8 + tt];
#pragma unroll
    for (int mf = 0; mf < 2; ++mf)
#pragma unroll
      for (int nf = 0; nf < 8; ++nf)
        s[mf][nf] = s[mf][nf] * C1;
    if (flg) {
      for (int mf = 0; mf < 2; ++mf)
        for (int nf = 0; nf < 8; ++nf)
          for (int r = 0; r < 4; ++r) {
            int frow = f0 + fbase + mf * 16 + g * 4 + r;
            int tcol = tt * 128 + nf * 16 + cc;
            s[mf][nf][r] += bf2f(adder[((size_t)b * SEQ + frow) * SEQ + tcol]);
          }
    }
#pragma unroll
    for (int mf = 0; mf < 2; ++mf)
#pragma unroll
      for (int r = 0; r < 4; ++r) {
        float tmax = s[mf][0][r];
#pragma unroll
        for (int nf = 1; nf < 8; ++nf) tmax = fmaxf(tmax, s[mf][nf][r]);
        tmax = fmaxf(tmax, __shfl_xor(tmax, 1, 16));
        tmax = fmaxf(tmax, __shfl_xor(tmax, 2, 16));
        tmax = fmaxf(tmax, __shfl_xor(tmax, 4, 16));
        tmax = fmaxf(tmax, __shfl_xor(tmax, 8, 16));
        int idx = mf * 4 + r;
        float mnew = fmaxf(m_run[idx], tmax);
        float sum = 0.f;
#pragma unroll
        for (int nf = 0; nf < 8; ++nf) sum += exp2f(s[mf][nf][r] - mnew);
        sum += __shfl_xor(sum, 1, 16);
        sum += __shfl_xor(sum, 2, 16);
        sum += __shfl_xor(sum, 4, 16);
        sum += __shfl_xor(sum, 8, 16);
        l_run[idx] = l_run[idx] * exp2f(m_run[idx] - mnew) + sum;
        m_run[idx] = mnew;
      }
  }

  float inv_l[8];
#pragma unroll
  for (int i = 0; i < 8; ++i) inv_l[i] = 1.0f / l_run[i];

  f32x4 accO[2][4] = {};

  // ---- pass 2: recompute S, write probs, accumulate ctx ----
  for (int tt = 0; tt < 8; ++tt) {
    __syncthreads();
#pragma unroll
    for (int i = 0; i < 4; ++i) {
      async16(&sK[sx[i]], Kg + (size_t)(tt * 128 + srow7[i]) * 64 + scol7[i]);
      async16(&sV[sx[i]], Vg + (size_t)srow8[i] * SEQ + tt * 128 + scol8[i]);
    }
    VMCNT0;
    __syncthreads();

    f32x4 s[2][8] = {};
#pragma unroll
    for (int kk = 0; kk < 2; ++kk) {
      bf16x8 aq[2], bk8[8];
#pragma unroll
      for (int mf = 0; mf < 2; ++mf) {
        int row = fbase + mf * 16 + cc;
        int colb = (kk * 64 + (g << 4)) ^ ((row & 7) << 4);
        aq[mf] = *(const bf16x8*)&sQ[(row * 128 + colb) >> 1];
      }
#pragma unroll
      for (int nf = 0; nf < 8; ++nf) {
        int row = nf * 16 + cc;
        int colb = (kk * 64 + (g << 4)) ^ ((row & 7) << 4);
        bk8[nf] = *(const bf16x8*)&sK[(row * 128 + colb) >> 1];
      }
#pragma unroll
      for (int mf = 0; mf < 2; ++mf)
#pragma unroll
        for (int nf = 0; nf < 8; ++nf)
          s[mf][nf] = __builtin_amdgcn_mfma_f32_16x16x32_bf16(aq[mf], bk8[nf], s[mf][nf], 0, 0, 0);
    }
    int flg = flags[(b * 8 + ft) * 8 + tt];
#pragma unroll
    for (int mf = 0; mf < 2; ++mf)
#pragma unroll
      for (int nf = 0; nf < 8; ++nf)
        s[mf][nf] = s[mf][nf] * C1;
    if (flg) {
      for (int mf = 0; mf < 2; ++mf)
        for (int nf = 0; nf < 8; ++nf)
          for (int r = 0; r < 4; ++r) {
            int frow = f0 + fbase + mf * 16 + g * 4 + r;
            int tcol = tt * 128 + nf * 16 + cc;
            s[mf][nf][r] += bf2f(adder[((size_t)b * SEQ + frow) * SEQ + tcol]);
          }
    }
#pragma unroll
    for (int mf = 0; mf < 2; ++mf)
#pragma unroll
      for (int nf = 0; nf < 8; ++nf)
#pragma unroll
        for (int r = 0; r < 4; ++r) {
          int idx = mf * 4 + r;
          float p = exp2f(s[mf][nf][r] - m_run[idx]) * inv_l[idx];
          int frow = fbase + mf * 16 + g * 4 + r;
          int tcol = nf * 16 + cc;
          probs[(((size_t)bh * SEQ) + f0 + frow) * SEQ + tt * 128 + tcol] = p;
          sP[(frow * 256 + ((tcol * 2) ^ ((frow & 7) << 4))) >> 1] = f2bf(p);
        }
#pragma unroll
    for (int ks = 0; ks < 4; ++ks) {
      bf16x8 ap[2], bv8[4];
#pragma unroll
      for (int mf = 0; mf < 2; ++mf) {
        int row = fbase + mf * 16 + cc;
        int colb = (ks * 64 + (g << 4)) ^ ((row & 7) << 4);
        ap[mf] = *(const bf16x8*)&sP[(row * 256 + colb) >> 1];
      }
#pragma unroll
      for (int nf = 0; nf < 4; ++nf) {
        int row = nf * 16 + cc;
        int colb = (ks * 64 + (g << 4)) ^ ((row & 7) << 4);
        bv8[nf] = *(const bf16x8*)&sV[(row * 256 + colb) >> 1];
      }
#pragma unroll
      for (int mf = 0; mf < 2; ++mf)
#pragma unroll
        for (int nf = 0; nf < 4; ++nf)
          accO[mf][nf] = __builtin_amdgcn_mfma_f32_16x16x32_bf16(ap[mf], bv8[nf], accO[mf][nf], 0, 0, 0);
    }
  }

#pragma unroll
  for (int mf = 0; mf < 2; ++mf)
#pragma unroll
    for (int nf = 0; nf < 4; ++nf)
#pragma unroll
      for (int r = 0; r < 4; ++r) {
        int frow = fbase + mf * 16 + g * 4 + r;
        int d = nf * 16 + cc;
        ctx[((size_t)b * SEQ + f0 + frow) * HIDDEN + h * 64 + d] = accO[mf][nf][r];
      }
}

extern "C" void kernel_launch(void* const* d_in, const int* in_sizes, int n_in,
                              void* d_out, int out_size, void* d_ws, size_t ws_size,
                              hipStream_t stream) {
  const float* from = (const float*)d_in[0];
  const float* to   = (const float*)d_in[1];
  const float* mask = (const float*)d_in[2];
  const float* Wq   = (const float*)d_in[3];
  const float* bq   = (const float*)d_in[4];
  const float* Wk   = (const float*)d_in[5];
  const float* bk   = (const float*)d_in[6];
  const float* Wv   = (const float*)d_in[7];
  const float* bv   = (const float*)d_in[8];

  char* ws = (char*)d_ws;
  u16* Af    = (u16*)(ws);
  u16* At    = (u16*)(ws + 8388608);
  u16* Wt    = (u16*)(ws + 16777216);
  u16* adder = (u16*)(ws + 23068672);
  int* flags = (int*)(ws + 31457280);
  u16* Qh    = (u16*)(ws + 31458304);
  u16* Kh    = (u16*)(ws + 39846912);
  u16* Vt    = (u16*)(ws + 48235520);

  float* ctx = (float*)d_out;
  float* probs = ctx + (size_t)BATCH * SEQ * HIDDEN;

  k_cvt<<<dim3(2048, 1, 2), 256, 0, stream>>>(from, Af, to, At, 524288);
  k_wtrans<<<dim3(16, 16, 3), 256, 0, stream>>>(Wq, Wk, Wv, Wt);
  k_mask<<<dim3(8, 8, 4), 256, 0, stream>>>(mask, adder, flags);
  k_gemm<<<dim3(8, 32, 3), 256, 0, stream>>>(Af, At, Wt, bq, bk, bv, Qh, Kh, Vt);
  k_attn<<<dim3(8, 16, 4), 256, 0, stream>>>(Qh, Kh, Vt, adder, flags, ctx, probs);
}